// Round 8
// baseline (350.969 us; speedup 1.0000x reference)
//
#include <hip/hip_runtime.h>

// Problem dims
#define L_DIM 2048
#define H_DIM 2048
#define D_DIM 4096
#define N_ST  16
#define R_TS  128
#define NPAD  256   // padded R+2N (160 -> 256)
#define NC    128   // scan chunks
#define CL    16    // steps per chunk (NC*CL = L)
#define KSP   8     // split-K factor for x_proj
#define KSPO  4     // split-K factor for out_proj

typedef unsigned short u16;
typedef short bf16x8 __attribute__((ext_vector_type(8)));
typedef float f32x4 __attribute__((ext_vector_type(4)));

__device__ __forceinline__ u16 f2b(float x) {
  union { float f; unsigned u; } v; v.f = x;
  unsigned r = v.u + 0x7fffu + ((v.u >> 16) & 1u);
  return (u16)(r >> 16);
}
__device__ __forceinline__ float b2f(u16 v) {
  union { unsigned u; float f; } x; x.u = (unsigned)v << 16; return x.f;
}

__device__ __forceinline__ void gl2lds16(const u16* g, u16* l) {
  __builtin_amdgcn_global_load_lds(
      (const __attribute__((address_space(1))) unsigned*)g,
      (__attribute__((address_space(3))) unsigned*)l, 16, 0, 0);
}

// ---------------- straight fp32 -> bf16 convert (vectorized) ----------------
__global__ __launch_bounds__(256)
void k_f32_to_bf16(const float* __restrict__ s, u16* __restrict__ d, int n4) {
  int i = blockIdx.x * 256 + threadIdx.x;
  if (i >= n4) return;
  float4 v = ((const float4*)s)[i];
  ushort4 o;
  o.x = f2b(v.x); o.y = f2b(v.y); o.z = f2b(v.z); o.w = f2b(v.w);
  ((ushort4*)d)[i] = o;
}

// ---------------- tiled transpose fp32 [R,C] -> bf16 [Cp,R], zero-pad C..Cp --
__global__ __launch_bounds__(256)
void k_transpose_bf16(const float* __restrict__ src, u16* __restrict__ dst,
                      int R, int C) {
  __shared__ float t[32][33];
  const int x = threadIdx.x, y = threadIdx.y;     // 32 x 8
  const int c0 = blockIdx.x * 32, r0 = blockIdx.y * 32;
#pragma unroll
  for (int i = 0; i < 4; ++i) {
    int r = r0 + y + i * 8, c = c0 + x;
    t[y + i * 8][x] = (c < C) ? src[(size_t)r * C + c] : 0.f;
  }
  __syncthreads();
#pragma unroll
  for (int i = 0; i < 4; ++i) {
    int cc = c0 + y + i * 8;
    dst[(size_t)cc * R + r0 + x] = f2b(t[x][y + i * 8]);
  }
}

// ============ 256x256 8-phase bf16 MFMA GEMM: C = A[M,K] * Bt[N,K]^T ========
// Output split into two bf16 [M, NS] buffers (cols < NS -> C0, else C1).
// NOTE: no XCD swizzle -- with gridDim.x=32 the default linear mapping gives
// XCD = bn%8 (good B-panel locality); round-7 swizzle tripled L2 fill traffic.
__global__ __launch_bounds__(512, 2)
void k_gemm256(const u16* __restrict__ A, const u16* __restrict__ Bt,
               u16* __restrict__ C0, u16* __restrict__ C1,
               int M, int N, int K, int NS) {
  __shared__ u16 lA[2][256][64];
  __shared__ u16 lB[2][256][64];
  const int tid = threadIdx.x;
  const int w = tid >> 6, lane = tid & 63;
  const int wm = w >> 2, wn = w & 3;          // 2 x 4 waves
  const int fr = lane & 15, fq = lane >> 4;
  const int xr = (fr & 7) << 4;               // read-side XOR (bytes)
  const int sr = lane >> 3;                   // stage row-in-group 0..7
  const int sc = ((lane & 7) ^ sr) << 3;      // stage source col (elems), pre-swizzled
  const int bn = blockIdx.x, bm = blockIdx.y;
  const u16* Ag = A + (size_t)bm * 256 * K;
  const u16* Bg = Bt + (size_t)bn * 256 * K;
  const int NT = K >> 6;

  f32x4 acc[8][4];
#pragma unroll
  for (int i = 0; i < 8; ++i)
#pragma unroll
    for (int j = 0; j < 4; ++j) acc[i][j] = (f32x4){0.f, 0.f, 0.f, 0.f};

  bf16x8 af[4][2];
  bf16x8 bfr[4][2];

#define STAGE_HALF(LT, G, TT, H) do {                                   \
    const int b_ = (TT) & 1; const int kt_ = (TT) << 6;                 \
    const u16* g0_ = (G) + (size_t)((H) * 128 + w * 8 + sr) * K + kt_ + sc; \
    u16* l0_ = &LT[b_][(H) * 128 + w * 8][0];                           \
    gl2lds16(g0_, l0_);                                                 \
    gl2lds16(g0_ + (size_t)64 * K, l0_ + 64 * 64);                      \
  } while (0)

#define LDA_HALF(BB, MH) do {                                           \
    const char* bA_ = (const char*)lA + (size_t)(BB) * 32768;           \
    _Pragma("unroll")                                                   \
    for (int m_ = 0; m_ < 4; ++m_) {                                    \
      const char* rp_ = bA_ + (wm * 128 + (MH) * 64 + m_ * 16 + fr) * 128; \
      af[m_][0] = *(const bf16x8*)(rp_ + ((fq << 4) ^ xr));             \
      af[m_][1] = *(const bf16x8*)(rp_ + ((64 | (fq << 4)) ^ xr));      \
    } } while (0)

#define LDB_HALF(BB, NH) do {                                           \
    const char* bB_ = (const char*)lB + (size_t)(BB) * 32768;           \
    _Pragma("unroll")                                                   \
    for (int n_ = 0; n_ < 2; ++n_) {                                    \
      const char* rp_ = bB_ + (wn * 64 + ((NH) * 2 + n_) * 16 + fr) * 128; \
      bfr[(NH) * 2 + n_][0] = *(const bf16x8*)(rp_ + ((fq << 4) ^ xr)); \
      bfr[(NH) * 2 + n_][1] = *(const bf16x8*)(rp_ + ((64 | (fq << 4)) ^ xr)); \
    } } while (0)

#define MFMA_Q(MH, NH) do {                                             \
    __builtin_amdgcn_s_setprio(1);                                      \
    _Pragma("unroll")                                                   \
    for (int m_ = 0; m_ < 4; ++m_)                                      \
      _Pragma("unroll")                                                 \
      for (int n_ = 0; n_ < 2; ++n_) {                                  \
        acc[(MH)*4+m_][(NH)*2+n_] = __builtin_amdgcn_mfma_f32_16x16x32_bf16( \
            af[m_][0], bfr[(NH)*2+n_][0], acc[(MH)*4+m_][(NH)*2+n_], 0, 0, 0); \
        acc[(MH)*4+m_][(NH)*2+n_] = __builtin_amdgcn_mfma_f32_16x16x32_bf16( \
            af[m_][1], bfr[(NH)*2+n_][1], acc[(MH)*4+m_][(NH)*2+n_], 0, 0, 0); \
      }                                                                 \
    __builtin_amdgcn_s_setprio(0);                                      \
  } while (0)

#define BAR() __builtin_amdgcn_s_barrier()
#define LGKM0() do { asm volatile("s_waitcnt lgkmcnt(0)" ::: "memory"); \
                     __builtin_amdgcn_sched_barrier(0); } while (0)

  STAGE_HALF(lA, Ag, 0, 0); STAGE_HALF(lA, Ag, 0, 1);
  STAGE_HALF(lB, Bg, 0, 0); STAGE_HALF(lB, Bg, 0, 1);
  STAGE_HALF(lB, Bg, 1, 0); STAGE_HALF(lB, Bg, 1, 1);
  asm volatile("s_waitcnt vmcnt(4)" ::: "memory");
  BAR();

  for (int t = 0; t < NT; ++t) {
    const int b = t & 1;
    const int ta = (t + 1 == NT) ? 0 : t + 1;
    const int tb = (t + 2 >= NT) ? (t + 2 - NT) : t + 2;
    LDA_HALF(b, 0); LDB_HALF(b, 0);
    STAGE_HALF(lA, Ag, ta, 0);
    BAR(); LGKM0();
    MFMA_Q(0, 0);
    BAR();
    LDB_HALF(b, 1);
    STAGE_HALF(lA, Ag, ta, 1);
    BAR(); LGKM0();
    MFMA_Q(0, 1);
    BAR();
    LDA_HALF(b, 1);
    STAGE_HALF(lB, Bg, tb, 0);
    BAR(); LGKM0();
    MFMA_Q(1, 0);
    BAR();
    STAGE_HALF(lB, Bg, tb, 1);
    BAR(); LGKM0();
    MFMA_Q(1, 1);
    asm volatile("s_waitcnt vmcnt(4)" ::: "memory");
    BAR();
  }
  asm volatile("s_waitcnt vmcnt(0)" ::: "memory");

#pragma unroll
  for (int mi = 0; mi < 8; ++mi)
#pragma unroll
    for (int n = 0; n < 4; ++n) {
      int col = bn * 256 + wn * 64 + n * 16 + fr;
      u16* Cd = C0;
      if (col >= NS) { Cd = C1; col -= NS; }
      const int row0 = bm * 256 + wm * 128 + mi * 16 + fq * 4;
#pragma unroll
      for (int j = 0; j < 4; ++j)
        Cd[(size_t)(row0 + j) * NS + col] = f2b(acc[mi][n][j]);
    }
}

// ===== split-K variant of the 8-phase 256^2 kernel: fp32 partials per z =====
// (round 5/6 measured: plain partial stores + separate reduce beat atomicAdd
//  epilogue by ~60 us -- device-scope fp32 atomics punch through per-XCD L2)
__global__ __launch_bounds__(512, 2)
void k_gemm256s(const u16* __restrict__ A, const u16* __restrict__ Bt,
                float* __restrict__ Cp, int M, int N, int K, int klen) {
  __shared__ u16 lA[2][256][64];
  __shared__ u16 lB[2][256][64];
  const int tid = threadIdx.x;
  const int w = tid >> 6, lane = tid & 63;
  const int wm = w >> 2, wn = w & 3;
  const int fr = lane & 15, fq = lane >> 4;
  const int xr = (fr & 7) << 4;
  const int sr = lane >> 3;
  const int sc = ((lane & 7) ^ sr) << 3;
  const int bn = blockIdx.x, bm = blockIdx.y, z = blockIdx.z;
  const int k0 = z * klen;
  const u16* Ag = A + (size_t)bm * 256 * K;
  const u16* Bg = Bt + (size_t)bn * 256 * K;
  const int NT = klen >> 6;
  float* C = Cp + (size_t)z * M * N;

  f32x4 acc[8][4];
#pragma unroll
  for (int i = 0; i < 8; ++i)
#pragma unroll
    for (int j = 0; j < 4; ++j) acc[i][j] = (f32x4){0.f, 0.f, 0.f, 0.f};

  bf16x8 af[4][2];
  bf16x8 bfr[4][2];

#undef STAGE_HALF
#define STAGE_HALF(LT, G, TT, H) do {                                   \
    const int b_ = (TT) & 1; const int kt_ = ((TT) << 6) + k0;          \
    const u16* g0_ = (G) + (size_t)((H) * 128 + w * 8 + sr) * K + kt_ + sc; \
    u16* l0_ = &LT[b_][(H) * 128 + w * 8][0];                           \
    gl2lds16(g0_, l0_);                                                 \
    gl2lds16(g0_ + (size_t)64 * K, l0_ + 64 * 64);                      \
  } while (0)

  STAGE_HALF(lA, Ag, 0, 0); STAGE_HALF(lA, Ag, 0, 1);
  STAGE_HALF(lB, Bg, 0, 0); STAGE_HALF(lB, Bg, 0, 1);
  STAGE_HALF(lB, Bg, 1, 0); STAGE_HALF(lB, Bg, 1, 1);
  asm volatile("s_waitcnt vmcnt(4)" ::: "memory");
  BAR();

  for (int t = 0; t < NT; ++t) {
    const int b = t & 1;
    const int ta = (t + 1 == NT) ? 0 : t + 1;
    const int tb = (t + 2 >= NT) ? (t + 2 - NT) : t + 2;
    LDA_HALF(b, 0); LDB_HALF(b, 0);
    STAGE_HALF(lA, Ag, ta, 0);
    BAR(); LGKM0();
    MFMA_Q(0, 0);
    BAR();
    LDB_HALF(b, 1);
    STAGE_HALF(lA, Ag, ta, 1);
    BAR(); LGKM0();
    MFMA_Q(0, 1);
    BAR();
    LDA_HALF(b, 1);
    STAGE_HALF(lB, Bg, tb, 0);
    BAR(); LGKM0();
    MFMA_Q(1, 0);
    BAR();
    STAGE_HALF(lB, Bg, tb, 1);
    BAR(); LGKM0();
    MFMA_Q(1, 1);
    asm volatile("s_waitcnt vmcnt(4)" ::: "memory");
    BAR();
  }
  asm volatile("s_waitcnt vmcnt(0)" ::: "memory");

#undef STAGE_HALF
#undef LDA_HALF
#undef LDB_HALF
#undef MFMA_Q
#undef BAR
#undef LGKM0

#pragma unroll
  for (int mi = 0; mi < 8; ++mi)
#pragma unroll
    for (int n = 0; n < 4; ++n) {
      const int col = bn * 256 + wn * 64 + n * 16 + fr;
      const int row0 = bm * 256 + wm * 128 + mi * 16 + fq * 4;
#pragma unroll
      for (int j = 0; j < 4; ++j)
        C[(size_t)(row0 + j) * N + col] = acc[mi][n][j];
    }
}

// -------- reduce out_proj split-K partials -> fp32 output -------------------
__global__ __launch_bounds__(256)
void k_ored(const float* __restrict__ Cp, float* __restrict__ out) {
  const int i = blockIdx.x * 256 + threadIdx.x;   // over M*N/4
  f32x4 s = (f32x4){0.f, 0.f, 0.f, 0.f};
#pragma unroll
  for (int z = 0; z < KSPO; ++z)
    s += *(const f32x4*)&Cp[(size_t)z * L_DIM * H_DIM + (size_t)i * 4];
  *(f32x4*)&out[(size_t)i * 4] = s;
}

// ---------------- bf16 MFMA GEMM (128x128, m97-style): C = A * Bt^T ---------
// bf16-output variant (dt_proj)
__global__ __launch_bounds__(256)
void k_gemm_bt16(const u16* __restrict__ A, const u16* __restrict__ Bt,
                 u16* __restrict__ C, int M, int N, int K) {
  __shared__ u16 sA[128 * 64];
  __shared__ u16 sB[128 * 64];
  const int tid = threadIdx.x;
  const int wave = tid >> 6, lane = tid & 63;
  const int bn = blockIdx.x, bm = blockIdx.y;
  const int wm = wave >> 1, wn = wave & 1;
  const int fr = lane & 15, fq = lane >> 4;
  const int srow = lane >> 3;
  const int scol = (lane & 7) * 8;

  const u16* Ab = A + (size_t)bm * 128 * K;
  const u16* Bb = Bt + (size_t)bn * 128 * K;

  f32x4 acc[4][4];
#pragma unroll
  for (int i = 0; i < 4; ++i)
#pragma unroll
    for (int j = 0; j < 4; ++j) acc[i][j] = (f32x4){0.f, 0.f, 0.f, 0.f};

  for (int kt = 0; kt < K; kt += 64) {
    __syncthreads();
#pragma unroll
    for (int i = 0; i < 4; ++i) {
      int ci = wave * 4 + i;
      int row = ci * 8 + srow;
      gl2lds16(Ab + (size_t)row * K + kt + scol, &sA[ci * 512]);
      gl2lds16(Bb + (size_t)row * K + kt + scol, &sB[ci * 512]);
    }
    __syncthreads();
#pragma unroll
    for (int kk = 0; kk < 2; ++kk) {
      bf16x8 af[4], bfr[4];
#pragma unroll
      for (int mf = 0; mf < 4; ++mf)
        af[mf] = *(const bf16x8*)&sA[(wm * 64 + mf * 16 + fr) * 64 + kk * 32 + fq * 8];
#pragma unroll
      for (int nf = 0; nf < 4; ++nf)
        bfr[nf] = *(const bf16x8*)&sB[(wn * 64 + nf * 16 + fr) * 64 + kk * 32 + fq * 8];
#pragma unroll
      for (int mf = 0; mf < 4; ++mf)
#pragma unroll
        for (int nf = 0; nf < 4; ++nf)
          acc[mf][nf] = __builtin_amdgcn_mfma_f32_16x16x32_bf16(
              af[mf], bfr[nf], acc[mf][nf], 0, 0, 0);
    }
  }

#pragma unroll
  for (int mf = 0; mf < 4; ++mf)
#pragma unroll
    for (int nf = 0; nf < 4; ++nf) {
      int col = bn * 128 + wn * 64 + nf * 16 + fr;
#pragma unroll
      for (int j = 0; j < 4; ++j) {
        int row = bm * 128 + wm * 64 + mf * 16 + fq * 4 + j;
        C[(size_t)row * N + col] = f2b(acc[mf][nf][j]);
      }
    }
}

// ---------------- split-K variant (blockIdx.z = K-slice), partial outputs ----
__global__ __launch_bounds__(256)
void k_gemm_bt_split(const u16* __restrict__ A, const u16* __restrict__ Bt,
                     float* __restrict__ Cp, int M, int N, int K, int klen) {
  __shared__ u16 sA[128 * 64];
  __shared__ u16 sB[128 * 64];
  const int tid = threadIdx.x;
  const int wave = tid >> 6, lane = tid & 63;
  const int bn = blockIdx.x, bm = blockIdx.y, z = blockIdx.z;
  const int wm = wave >> 1, wn = wave & 1;
  const int fr = lane & 15, fq = lane >> 4;
  const int srow = lane >> 3;
  const int scol = (lane & 7) * 8;
  const int k0 = z * klen;
  float* C = Cp + (size_t)z * M * N;

  const u16* Ab = A + (size_t)bm * 128 * K;
  const u16* Bb = Bt + (size_t)bn * 128 * K;

  f32x4 acc[4][4];
#pragma unroll
  for (int i = 0; i < 4; ++i)
#pragma unroll
    for (int j = 0; j < 4; ++j) acc[i][j] = (f32x4){0.f, 0.f, 0.f, 0.f};

  for (int kt = k0; kt < k0 + klen; kt += 64) {
    __syncthreads();
#pragma unroll
    for (int i = 0; i < 4; ++i) {
      int ci = wave * 4 + i;
      int row = ci * 8 + srow;
      gl2lds16(Ab + (size_t)row * K + kt + scol, &sA[ci * 512]);
      gl2lds16(Bb + (size_t)row * K + kt + scol, &sB[ci * 512]);
    }
    __syncthreads();
#pragma unroll
    for (int kk = 0; kk < 2; ++kk) {
      bf16x8 af[4], bfr[4];
#pragma unroll
      for (int mf = 0; mf < 4; ++mf)
        af[mf] = *(const bf16x8*)&sA[(wm * 64 + mf * 16 + fr) * 64 + kk * 32 + fq * 8];
#pragma unroll
      for (int nf = 0; nf < 4; ++nf)
        bfr[nf] = *(const bf16x8*)&sB[(wn * 64 + nf * 16 + fr) * 64 + kk * 32 + fq * 8];
#pragma unroll
      for (int mf = 0; mf < 4; ++mf)
#pragma unroll
        for (int nf = 0; nf < 4; ++nf)
          acc[mf][nf] = __builtin_amdgcn_mfma_f32_16x16x32_bf16(
              af[mf], bfr[nf], acc[mf][nf], 0, 0, 0);
    }
  }

#pragma unroll
  for (int mf = 0; mf < 4; ++mf)
#pragma unroll
    for (int nf = 0; nf < 4; ++nf) {
      int col = bn * 128 + wn * 64 + nf * 16 + fr;
#pragma unroll
      for (int j = 0; j < 4; ++j) {
        int row = bm * 128 + wm * 64 + mf * 16 + fq * 4 + j;
        C[(size_t)row * N + col] = acc[mf][nf][j];
      }
    }
}

// -------- reduce split-K partials -> ssm fp32; fuse time_step bf16 extract ---
__global__ __launch_bounds__(256)
void k_xred(const float* __restrict__ Cp, float* __restrict__ ssm,
            u16* __restrict__ tsb) {
  int i = blockIdx.x * 256 + threadIdx.x;   // over L*NPAD/4
  int l = i >> 6, g = i & 63;
  f32x4 s = (f32x4){0.f, 0.f, 0.f, 0.f};
#pragma unroll
  for (int z = 0; z < KSP; ++z)
    s += *(const f32x4*)&Cp[(size_t)z * L_DIM * NPAD + (size_t)l * NPAD + g * 4];
  *(f32x4*)&ssm[(size_t)l * NPAD + g * 4] = s;
  if (g < 32) {
    ushort4 o;
    o.x = f2b(s[0]); o.y = f2b(s[1]); o.z = f2b(s[2]); o.w = f2b(s[3]);
    *(ushort4*)&tsb[(size_t)l * R_TS + g * 4] = o;
  }
}

// ---------------- depthwise causal conv (K=4) + bias + silu -> bf16 ---------
__global__ __launch_bounds__(256)
void k_conv_silu(const u16* __restrict__ Phid, const float* __restrict__ ck,
                 const float* __restrict__ cb, u16* __restrict__ hb) {
  int idx = blockIdx.x * 256 + threadIdx.x;       // over L*D/4
  int l = idx >> 10, d0 = (idx & 1023) * 4;       // D/4 = 1024
  float4 a = *(const float4*)&cb[d0];
#pragma unroll
  for (int k = 0; k < 4; ++k) {
    int ll = l - 3 + k;
    if (ll >= 0) {
      ushort4 pv = *(const ushort4*)&Phid[(size_t)ll * D_DIM + d0];
      a.x = fmaf(b2f(pv.x), ck[(d0 + 0) * 4 + k], a.x);
      a.y = fmaf(b2f(pv.y), ck[(d0 + 1) * 4 + k], a.y);
      a.z = fmaf(b2f(pv.z), ck[(d0 + 2) * 4 + k], a.z);
      a.w = fmaf(b2f(pv.w), ck[(d0 + 3) * 4 + k], a.w);
    }
  }
  ushort4 o;
  o.x = f2b(a.x / (1.f + __expf(-a.x)));
  o.y = f2b(a.y / (1.f + __expf(-a.y)));
  o.z = f2b(a.z / (1.f + __expf(-a.z)));
  o.w = f2b(a.w / (1.f + __expf(-a.w)));
  *(ushort4*)&hb[(size_t)l * D_DIM + d0] = o;
}

// ---------------- chunked selective scan (NC=128, CL=16) ----------------
__global__ __launch_bounds__(256)
void k_scan_partial(const u16* __restrict__ dtraw, const float* __restrict__ b_dt,
                    const u16* __restrict__ hb, const float* __restrict__ ssm,
                    const float* __restrict__ A_log, float* __restrict__ sC,
                    float* __restrict__ aP) {
  __shared__ float sBl[CL][16];
  const int c = blockIdx.x >> 4;
  const int d = ((blockIdx.x & 15) << 8) + threadIdx.x;
  const int l0 = c * CL;
  {
    int t = threadIdx.x;
    if (t < CL * 4) {
      int r = t >> 2, j = (t & 3) * 4;
      *(float4*)&sBl[r][j] =
          *(const float4*)&ssm[(size_t)(l0 + r) * NPAD + R_TS + j];
    }
  }
  float Ac[N_ST];
#pragma unroll
  for (int n = 0; n < N_ST; ++n) Ac[n] = -__expf(A_log[d * N_ST + n]);
  const float bdt = b_dt[d];
  float s[N_ST], ap[N_ST];
#pragma unroll
  for (int n = 0; n < N_ST; ++n) { s[n] = 0.f; ap[n] = 1.f; }
  __syncthreads();

  float dtn = b2f(dtraw[(size_t)l0 * D_DIM + d]);
  float hn = b2f(hb[(size_t)l0 * D_DIM + d]);
  for (int i = 0; i < CL; ++i) {
    const float x = dtn + bdt;
    const float hv = hn;
    const int ip = (i + 1 < CL) ? (i + 1) : i;
    dtn = b2f(dtraw[(size_t)(l0 + ip) * D_DIM + d]);
    hn = b2f(hb[(size_t)(l0 + ip) * D_DIM + d]);
    const float dt = (x > 20.f) ? x : __logf(1.f + __expf(x));
    const float dth = dt * hv;
#pragma unroll
    for (int n = 0; n < N_ST; ++n) {
      float dA = __expf(Ac[n] * dt);
      s[n] = fmaf(dA, s[n], dth * sBl[i][n]);
      ap[n] *= dA;
    }
  }
  float* so = sC + ((size_t)c * D_DIM + d) * N_ST;
  float* ao = aP + ((size_t)c * D_DIM + d) * N_ST;
#pragma unroll
  for (int n = 0; n < N_ST; ++n) { so[n] = s[n]; ao[n] = ap[n]; }
}

__global__ __launch_bounds__(256)
void k_scan_combine(const float* __restrict__ sC, const float* __restrict__ aP,
                    float* __restrict__ init) {
  const int i = blockIdx.x * 256 + threadIdx.x;
  float s = 0.f;
  for (int c = 0; c < NC; ++c) {
    init[(size_t)c * (D_DIM * N_ST) + i] = s;
    s = fmaf(aP[(size_t)c * (D_DIM * N_ST) + i], s,
             sC[(size_t)c * (D_DIM * N_ST) + i]);
  }
}

__global__ __launch_bounds__(256)
void k_scan_final(const u16* __restrict__ dtraw, const float* __restrict__ b_dt,
                  const u16* __restrict__ hb, const float* __restrict__ ssm,
                  const float* __restrict__ A_log, const float* __restrict__ init,
                  const u16* __restrict__ Pgate, const float* __restrict__ Dp,
                  u16* __restrict__ yb) {
  __shared__ float sBC[CL][32];
  const int c = blockIdx.x >> 4;
  const int d = ((blockIdx.x & 15) << 8) + threadIdx.x;
  const int l0 = c * CL;
  {
    int t = threadIdx.x;
    if (t < CL * 8) {
      int r = t >> 3, j = (t & 7) * 4;
      *(float4*)&sBC[r][j] =
          *(const float4*)&ssm[(size_t)(l0 + r) * NPAD + R_TS + j];
    }
  }
  float Ac[N_ST];
#pragma unroll
  for (int n = 0; n < N_ST; ++n) Ac[n] = -__expf(A_log[d * N_ST + n]);
  const float bdt = b_dt[d], dpd = Dp[d];
  float s[N_ST];
  const float* ini = init + ((size_t)c * D_DIM + d) * N_ST;
#pragma unroll
  for (int n = 0; n < N_ST; ++n) s[n] = ini[n];
  __syncthreads();

  float dtn = b2f(dtraw[(size_t)l0 * D_DIM + d]);
  float hn = b2f(hb[(size_t)l0 * D_DIM + d]);
  float gn = b2f(Pgate[(size_t)l0 * D_DIM + d]);
  for (int i = 0; i < CL; ++i) {
    const float x = dtn + bdt;
    const float hv = hn;
    const float gv = gn;
    const int ip = (i + 1 < CL) ? (i + 1) : i;
    dtn = b2f(dtraw[(size_t)(l0 + ip) * D_DIM + d]);
    hn = b2f(hb[(size_t)(l0 + ip) * D_DIM + d]);
    gn = b2f(Pgate[(size_t)(l0 + ip) * D_DIM + d]);
    const float dt = (x > 20.f) ? x : __logf(1.f + __expf(x));
    const float dth = dt * hv;
    float y = 0.f;
#pragma unroll
    for (int n = 0; n < N_ST; ++n) {
      float dA = __expf(Ac[n] * dt);
      s[n] = fmaf(dA, s[n], dth * sBC[i][n]);
      y = fmaf(s[n], sBC[i][16 + n], y);
    }
    y = fmaf(hv, dpd, y);
    const float sg = gv / (1.f + __expf(-gv));
    yb[(size_t)(l0 + i) * D_DIM + d] = f2b(y * sg);
  }
}

// ---------------- launcher ----------------
extern "C" void kernel_launch(void* const* d_in, const int* in_sizes, int n_in,
                              void* d_out, int out_size, void* d_ws, size_t ws_size,
                              hipStream_t stream) {
  const float* X     = (const float*)d_in[0];
  const float* W_in  = (const float*)d_in[1];
  const float* ck    = (const float*)d_in[2];
  const float* cb    = (const float*)d_in[3];
  const float* W_x   = (const float*)d_in[4];
  const float* W_dt  = (const float*)d_in[5];
  const float* b_dt  = (const float*)d_in[6];
  const float* W_out = (const float*)d_in[7];
  const float* A_log = (const float*)d_in[8];
  const float* Dp    = (const float*)d_in[9];

  char* w = (char*)d_ws;
  size_t off = 0;
  auto alloc = [&](size_t bytes) {
    void* p = w + off;
    off = (off + bytes + 255) & ~(size_t)255;
    return p;
  };
  u16*   Xb    = (u16*)  alloc((size_t)L_DIM * H_DIM * 2);        //  0.0 -  8.4 MB
  u16*   WinT  = (u16*)  alloc((size_t)2 * D_DIM * H_DIM * 2);    //  8.4 - 42.0
  u16*   Phid  = (u16*)  alloc((size_t)L_DIM * D_DIM * 2);        // 42.0 - 58.8
  u16*   Pgate = (u16*)  alloc((size_t)L_DIM * D_DIM * 2);        // 58.8 - 75.6
  u16*   hb    = (u16*)  alloc((size_t)L_DIM * D_DIM * 2);        // 75.6 - 92.4
  u16*   WxT   = (u16*)  alloc((size_t)NPAD * D_DIM * 2);
  float* ssm   = (float*)alloc((size_t)L_DIM * NPAD * 4);
  u16*   tsb   = (u16*)  alloc((size_t)L_DIM * R_TS * 2);
  u16*   WdtT  = (u16*)  alloc((size_t)D_DIM * R_TS * 2);
  u16*   dtraw = (u16*)  alloc((size_t)L_DIM * D_DIM * 2);        // bf16
  u16*   WoutT = (u16*)  alloc((size_t)H_DIM * D_DIM * 2);
  u16*   yb    = (u16*)  alloc((size_t)L_DIM * D_DIM * 2);        // ~149 MB linear
  // NC=128: sC/aP/init are 33.6 MB each.
  //  sCb   @0 (Xb+WinT region 0-42 MB, dead after step 3)            [steps 10-11]
  //  aPb   fresh tail alloc                                          [steps 10-11]
  //  initb fresh tail alloc                                          [steps 11-12]
  //  xpart (16.8 MB) @0                                              [steps 6-7]
  //  opart (67.1 MB) @0 covers Xb,WinT,Phid,Pgate - all dead by 14   [steps 14-15]
  float* xpart = (float*)d_ws;
  float* sCb   = (float*)d_ws;
  float* aPb   = (float*)alloc((size_t)NC * D_DIM * N_ST * 4);    // +33.6
  float* initb = (float*)alloc((size_t)NC * D_DIM * N_ST * 4);    // +33.6 -> ~216 MB
  float* opart = (float*)d_ws;
  (void)ws_size;

  // 1) X -> bf16
  k_f32_to_bf16<<<(L_DIM * H_DIM / 4 + 255) / 256, 256, 0, stream>>>(
      X, Xb, L_DIM * H_DIM / 4);
  // 2) W_in [H,2D] -> WinT [2D,H]
  k_transpose_bf16<<<dim3(2 * D_DIM / 32, H_DIM / 32), dim3(32, 8), 0, stream>>>(
      W_in, WinT, H_DIM, 2 * D_DIM);
  // 3) {Phid|Pgate} = X * W_in   (8-phase 256^2, bf16 outputs)
  k_gemm256<<<dim3(2 * D_DIM / 256, L_DIM / 256), 512, 0, stream>>>(
      Xb, WinT, Phid, Pgate, L_DIM, 2 * D_DIM, H_DIM, D_DIM);
  // 4) conv + silu -> hb (bf16), 4-wide vectorized
  k_conv_silu<<<L_DIM * D_DIM / 4 / 256, 256, 0, stream>>>(Phid, ck, cb, hb);
  // 5) W_x [D,160] -> WxT [256,D] zero-padded
  k_transpose_bf16<<<dim3(NPAD / 32, D_DIM / 32), dim3(32, 8), 0, stream>>>(
      W_x, WxT, D_DIM, R_TS + 2 * N_ST);
  // 6-7) ssm partials = h * W_x  (split-K=8), reduce + ts extract
  k_gemm_bt_split<<<dim3(NPAD / 128, L_DIM / 128, KSP), 256, 0, stream>>>(
      hb, WxT, xpart, L_DIM, NPAD, D_DIM, D_DIM / KSP);
  k_xred<<<L_DIM * NPAD / 4 / 256, 256, 0, stream>>>(xpart, ssm, tsb);
  // 8) W_dt [128,D] -> WdtT [D,128]
  k_transpose_bf16<<<dim3(D_DIM / 32, R_TS / 32), dim3(32, 8), 0, stream>>>(
      W_dt, WdtT, R_TS, D_DIM);
  // 9) dtraw = ts * W_dt  [L, D] (bf16 out)
  k_gemm_bt16<<<dim3(D_DIM / 128, L_DIM / 128), 256, 0, stream>>>(
      tsb, WdtT, dtraw, L_DIM, D_DIM, R_TS);
  // 10-12) chunked scan (NC=128 chunks of CL=16)
  k_scan_partial<<<NC * (D_DIM / 256), 256, 0, stream>>>(
      dtraw, b_dt, hb, ssm, A_log, sCb, aPb);
  k_scan_combine<<<D_DIM * N_ST / 256, 256, 0, stream>>>(sCb, aPb, initb);
  k_scan_final<<<NC * (D_DIM / 256), 256, 0, stream>>>(
      dtraw, b_dt, hb, ssm, A_log, initb, Pgate, Dp, yb);
  // 13) W_out [D,H] -> WoutT [H,D]
  k_transpose_bf16<<<dim3(H_DIM / 32, D_DIM / 32), dim3(32, 8), 0, stream>>>(
      W_out, WoutT, D_DIM, H_DIM);
  // 14-15) out = y * W_out  (8-phase 256^2, split-K=4) + reduce
  k_gemm256s<<<dim3(H_DIM / 256, L_DIM / 256, KSPO), 512, 0, stream>>>(
      yb, WoutT, opart, L_DIM, H_DIM, D_DIM, D_DIM / KSPO);
  k_ored<<<L_DIM * H_DIM / 4 / 256, 256, 0, stream>>>(opart, (float*)d_out);
}

// Round 9
// 339.113 us; speedup vs baseline: 1.0350x; 1.0350x over previous
//
#include <hip/hip_runtime.h>

// Problem dims
#define L_DIM 2048
#define H_DIM 2048
#define D_DIM 4096
#define N_ST  16
#define R_TS  128
#define NPAD  256   // padded R+2N (160 -> 256)
#define NC    64    // scan chunks (64 proven best: 128 regressed, r8)
#define CL    32    // steps per chunk (NC*CL = L)
#define KSP   8     // split-K factor for x_proj
#define KSPO  4     // split-K factor for out_proj

typedef unsigned short u16;
typedef short bf16x8 __attribute__((ext_vector_type(8)));
typedef float f32x4 __attribute__((ext_vector_type(4)));

__device__ __forceinline__ u16 f2b(float x) {
  union { float f; unsigned u; } v; v.f = x;
  unsigned r = v.u + 0x7fffu + ((v.u >> 16) & 1u);
  return (u16)(r >> 16);
}
__device__ __forceinline__ float b2f(u16 v) {
  union { unsigned u; float f; } x; x.u = (unsigned)v << 16; return x.f;
}

__device__ __forceinline__ void gl2lds16(const u16* g, u16* l) {
  __builtin_amdgcn_global_load_lds(
      (const __attribute__((address_space(1))) unsigned*)g,
      (__attribute__((address_space(3))) unsigned*)l, 16, 0, 0);
}

// ---------------- straight fp32 -> bf16 convert (vectorized) ----------------
__global__ __launch_bounds__(256)
void k_f32_to_bf16(const float* __restrict__ s, u16* __restrict__ d, int n4) {
  int i = blockIdx.x * 256 + threadIdx.x;
  if (i >= n4) return;
  float4 v = ((const float4*)s)[i];
  ushort4 o;
  o.x = f2b(v.x); o.y = f2b(v.y); o.z = f2b(v.z); o.w = f2b(v.w);
  ((ushort4*)d)[i] = o;
}

// ---------------- tiled transpose fp32 [R,C] -> bf16 [Cp,R], zero-pad C..Cp --
__global__ __launch_bounds__(256)
void k_transpose_bf16(const float* __restrict__ src, u16* __restrict__ dst,
                      int R, int C) {
  __shared__ float t[32][33];
  const int x = threadIdx.x, y = threadIdx.y;     // 32 x 8
  const int c0 = blockIdx.x * 32, r0 = blockIdx.y * 32;
#pragma unroll
  for (int i = 0; i < 4; ++i) {
    int r = r0 + y + i * 8, c = c0 + x;
    t[y + i * 8][x] = (c < C) ? src[(size_t)r * C + c] : 0.f;
  }
  __syncthreads();
#pragma unroll
  for (int i = 0; i < 4; ++i) {
    int cc = c0 + y + i * 8;
    dst[(size_t)cc * R + r0 + x] = f2b(t[x][y + i * 8]);
  }
}

// ============ 256x256 8-phase bf16 MFMA GEMM: C = A[M,K] * Bt[N,K]^T ========
// Output split into two bf16 [M, NS] buffers (cols < NS -> C0, else C1).
// No XCD swizzle: with gridDim.x=32 the linear mapping gives XCD = bn%8
// (B-panel per-XCD L2 locality); r7 swizzle tripled FETCH (143 MB) for 0 gain.
__global__ __launch_bounds__(512, 2)
void k_gemm256(const u16* __restrict__ A, const u16* __restrict__ Bt,
               u16* __restrict__ C0, u16* __restrict__ C1,
               int M, int N, int K, int NS) {
  __shared__ u16 lA[2][256][64];
  __shared__ u16 lB[2][256][64];
  const int tid = threadIdx.x;
  const int w = tid >> 6, lane = tid & 63;
  const int wm = w >> 2, wn = w & 3;          // 2 x 4 waves
  const int fr = lane & 15, fq = lane >> 4;
  const int xr = (fr & 7) << 4;               // read-side XOR (bytes)
  const int sr = lane >> 3;                   // stage row-in-group 0..7
  const int sc = ((lane & 7) ^ sr) << 3;      // stage source col (elems), pre-swizzled
  const int bn = blockIdx.x, bm = blockIdx.y;
  const u16* Ag = A + (size_t)bm * 256 * K;
  const u16* Bg = Bt + (size_t)bn * 256 * K;
  const int NT = K >> 6;

  f32x4 acc[8][4];
#pragma unroll
  for (int i = 0; i < 8; ++i)
#pragma unroll
    for (int j = 0; j < 4; ++j) acc[i][j] = (f32x4){0.f, 0.f, 0.f, 0.f};

  bf16x8 af[4][2];
  bf16x8 bfr[4][2];

#define STAGE_HALF(LT, G, TT, H) do {                                   \
    const int b_ = (TT) & 1; const int kt_ = (TT) << 6;                 \
    const u16* g0_ = (G) + (size_t)((H) * 128 + w * 8 + sr) * K + kt_ + sc; \
    u16* l0_ = &LT[b_][(H) * 128 + w * 8][0];                           \
    gl2lds16(g0_, l0_);                                                 \
    gl2lds16(g0_ + (size_t)64 * K, l0_ + 64 * 64);                      \
  } while (0)

#define LDA_HALF(BB, MH) do {                                           \
    const char* bA_ = (const char*)lA + (size_t)(BB) * 32768;           \
    _Pragma("unroll")                                                   \
    for (int m_ = 0; m_ < 4; ++m_) {                                    \
      const char* rp_ = bA_ + (wm * 128 + (MH) * 64 + m_ * 16 + fr) * 128; \
      af[m_][0] = *(const bf16x8*)(rp_ + ((fq << 4) ^ xr));             \
      af[m_][1] = *(const bf16x8*)(rp_ + ((64 | (fq << 4)) ^ xr));      \
    } } while (0)

#define LDB_HALF(BB, NH) do {                                           \
    const char* bB_ = (const char*)lB + (size_t)(BB) * 32768;           \
    _Pragma("unroll")                                                   \
    for (int n_ = 0; n_ < 2; ++n_) {                                    \
      const char* rp_ = bB_ + (wn * 64 + ((NH) * 2 + n_) * 16 + fr) * 128; \
      bfr[(NH) * 2 + n_][0] = *(const bf16x8*)(rp_ + ((fq << 4) ^ xr)); \
      bfr[(NH) * 2 + n_][1] = *(const bf16x8*)(rp_ + ((64 | (fq << 4)) ^ xr)); \
    } } while (0)

#define MFMA_Q(MH, NH) do {                                             \
    __builtin_amdgcn_s_setprio(1);                                      \
    _Pragma("unroll")                                                   \
    for (int m_ = 0; m_ < 4; ++m_)                                      \
      _Pragma("unroll")                                                 \
      for (int n_ = 0; n_ < 2; ++n_) {                                  \
        acc[(MH)*4+m_][(NH)*2+n_] = __builtin_amdgcn_mfma_f32_16x16x32_bf16( \
            af[m_][0], bfr[(NH)*2+n_][0], acc[(MH)*4+m_][(NH)*2+n_], 0, 0, 0); \
        acc[(MH)*4+m_][(NH)*2+n_] = __builtin_amdgcn_mfma_f32_16x16x32_bf16( \
            af[m_][1], bfr[(NH)*2+n_][1], acc[(MH)*4+m_][(NH)*2+n_], 0, 0, 0); \
      }                                                                 \
    __builtin_amdgcn_s_setprio(0);                                      \
  } while (0)

#define BAR() __builtin_amdgcn_s_barrier()
#define LGKM0() do { asm volatile("s_waitcnt lgkmcnt(0)" ::: "memory"); \
                     __builtin_amdgcn_sched_barrier(0); } while (0)

  STAGE_HALF(lA, Ag, 0, 0); STAGE_HALF(lA, Ag, 0, 1);
  STAGE_HALF(lB, Bg, 0, 0); STAGE_HALF(lB, Bg, 0, 1);
  STAGE_HALF(lB, Bg, 1, 0); STAGE_HALF(lB, Bg, 1, 1);
  asm volatile("s_waitcnt vmcnt(4)" ::: "memory");
  BAR();

  for (int t = 0; t < NT; ++t) {
    const int b = t & 1;
    const int ta = (t + 1 == NT) ? 0 : t + 1;
    const int tb = (t + 2 >= NT) ? (t + 2 - NT) : t + 2;
    LDA_HALF(b, 0); LDB_HALF(b, 0);
    STAGE_HALF(lA, Ag, ta, 0);
    BAR(); LGKM0();
    MFMA_Q(0, 0);
    BAR();
    LDB_HALF(b, 1);
    STAGE_HALF(lA, Ag, ta, 1);
    BAR(); LGKM0();
    MFMA_Q(0, 1);
    BAR();
    LDA_HALF(b, 1);
    STAGE_HALF(lB, Bg, tb, 0);
    BAR(); LGKM0();
    MFMA_Q(1, 0);
    BAR();
    STAGE_HALF(lB, Bg, tb, 1);
    BAR(); LGKM0();
    MFMA_Q(1, 1);
    asm volatile("s_waitcnt vmcnt(4)" ::: "memory");
    BAR();
  }
  asm volatile("s_waitcnt vmcnt(0)" ::: "memory");

#pragma unroll
  for (int mi = 0; mi < 8; ++mi)
#pragma unroll
    for (int n = 0; n < 4; ++n) {
      int col = bn * 256 + wn * 64 + n * 16 + fr;
      u16* Cd = C0;
      if (col >= NS) { Cd = C1; col -= NS; }
      const int row0 = bm * 256 + wm * 128 + mi * 16 + fq * 4;
#pragma unroll
      for (int j = 0; j < 4; ++j)
        Cd[(size_t)(row0 + j) * NS + col] = f2b(acc[mi][n][j]);
    }
}

// ===== split-K 8-phase 256^2 kernel: bf16 partials per z (halved traffic) ===
// (r5/r6 measured: partial stores + separate reduce >> atomicAdd epilogue)
__global__ __launch_bounds__(512, 2)
void k_gemm256s(const u16* __restrict__ A, const u16* __restrict__ Bt,
                u16* __restrict__ Cp, int M, int N, int K, int klen) {
  __shared__ u16 lA[2][256][64];
  __shared__ u16 lB[2][256][64];
  const int tid = threadIdx.x;
  const int w = tid >> 6, lane = tid & 63;
  const int wm = w >> 2, wn = w & 3;
  const int fr = lane & 15, fq = lane >> 4;
  const int xr = (fr & 7) << 4;
  const int sr = lane >> 3;
  const int sc = ((lane & 7) ^ sr) << 3;
  const int bn = blockIdx.x, bm = blockIdx.y, z = blockIdx.z;
  const int k0 = z * klen;
  const u16* Ag = A + (size_t)bm * 256 * K;
  const u16* Bg = Bt + (size_t)bn * 256 * K;
  const int NT = klen >> 6;
  u16* C = Cp + (size_t)z * M * N;

  f32x4 acc[8][4];
#pragma unroll
  for (int i = 0; i < 8; ++i)
#pragma unroll
    for (int j = 0; j < 4; ++j) acc[i][j] = (f32x4){0.f, 0.f, 0.f, 0.f};

  bf16x8 af[4][2];
  bf16x8 bfr[4][2];

#undef STAGE_HALF
#define STAGE_HALF(LT, G, TT, H) do {                                   \
    const int b_ = (TT) & 1; const int kt_ = ((TT) << 6) + k0;          \
    const u16* g0_ = (G) + (size_t)((H) * 128 + w * 8 + sr) * K + kt_ + sc; \
    u16* l0_ = &LT[b_][(H) * 128 + w * 8][0];                           \
    gl2lds16(g0_, l0_);                                                 \
    gl2lds16(g0_ + (size_t)64 * K, l0_ + 64 * 64);                      \
  } while (0)

  STAGE_HALF(lA, Ag, 0, 0); STAGE_HALF(lA, Ag, 0, 1);
  STAGE_HALF(lB, Bg, 0, 0); STAGE_HALF(lB, Bg, 0, 1);
  STAGE_HALF(lB, Bg, 1, 0); STAGE_HALF(lB, Bg, 1, 1);
  asm volatile("s_waitcnt vmcnt(4)" ::: "memory");
  BAR();

  for (int t = 0; t < NT; ++t) {
    const int b = t & 1;
    const int ta = (t + 1 == NT) ? 0 : t + 1;
    const int tb = (t + 2 >= NT) ? (t + 2 - NT) : t + 2;
    LDA_HALF(b, 0); LDB_HALF(b, 0);
    STAGE_HALF(lA, Ag, ta, 0);
    BAR(); LGKM0();
    MFMA_Q(0, 0);
    BAR();
    LDB_HALF(b, 1);
    STAGE_HALF(lA, Ag, ta, 1);
    BAR(); LGKM0();
    MFMA_Q(0, 1);
    BAR();
    LDA_HALF(b, 1);
    STAGE_HALF(lB, Bg, tb, 0);
    BAR(); LGKM0();
    MFMA_Q(1, 0);
    BAR();
    STAGE_HALF(lB, Bg, tb, 1);
    BAR(); LGKM0();
    MFMA_Q(1, 1);
    asm volatile("s_waitcnt vmcnt(4)" ::: "memory");
    BAR();
  }
  asm volatile("s_waitcnt vmcnt(0)" ::: "memory");

#undef STAGE_HALF
#undef LDA_HALF
#undef LDB_HALF
#undef MFMA_Q
#undef BAR
#undef LGKM0

#pragma unroll
  for (int mi = 0; mi < 8; ++mi)
#pragma unroll
    for (int n = 0; n < 4; ++n) {
      const int col = bn * 256 + wn * 64 + n * 16 + fr;
      const int row0 = bm * 256 + wm * 128 + mi * 16 + fq * 4;
#pragma unroll
      for (int j = 0; j < 4; ++j)
        C[(size_t)(row0 + j) * N + col] = f2b(acc[mi][n][j]);
    }
}

// -------- reduce out_proj bf16 split-K partials -> fp32 output --------------
__global__ __launch_bounds__(256)
void k_ored(const u16* __restrict__ Cp, float* __restrict__ out) {
  const int i = blockIdx.x * 256 + threadIdx.x;   // over M*N/4
  f32x4 s = (f32x4){0.f, 0.f, 0.f, 0.f};
#pragma unroll
  for (int z = 0; z < KSPO; ++z) {
    ushort4 p = *(const ushort4*)&Cp[(size_t)z * L_DIM * H_DIM + (size_t)i * 4];
    s[0] += b2f(p.x); s[1] += b2f(p.y); s[2] += b2f(p.z); s[3] += b2f(p.w);
  }
  *(f32x4*)&out[(size_t)i * 4] = s;
}

// ---------------- bf16 MFMA GEMM (128x128, m97-style): C = A * Bt^T ---------
// bf16-output variant (dt_proj)
__global__ __launch_bounds__(256)
void k_gemm_bt16(const u16* __restrict__ A, const u16* __restrict__ Bt,
                 u16* __restrict__ C, int M, int N, int K) {
  __shared__ u16 sA[128 * 64];
  __shared__ u16 sB[128 * 64];
  const int tid = threadIdx.x;
  const int wave = tid >> 6, lane = tid & 63;
  const int bn = blockIdx.x, bm = blockIdx.y;
  const int wm = wave >> 1, wn = wave & 1;
  const int fr = lane & 15, fq = lane >> 4;
  const int srow = lane >> 3;
  const int scol = (lane & 7) * 8;

  const u16* Ab = A + (size_t)bm * 128 * K;
  const u16* Bb = Bt + (size_t)bn * 128 * K;

  f32x4 acc[4][4];
#pragma unroll
  for (int i = 0; i < 4; ++i)
#pragma unroll
    for (int j = 0; j < 4; ++j) acc[i][j] = (f32x4){0.f, 0.f, 0.f, 0.f};

  for (int kt = 0; kt < K; kt += 64) {
    __syncthreads();
#pragma unroll
    for (int i = 0; i < 4; ++i) {
      int ci = wave * 4 + i;
      int row = ci * 8 + srow;
      gl2lds16(Ab + (size_t)row * K + kt + scol, &sA[ci * 512]);
      gl2lds16(Bb + (size_t)row * K + kt + scol, &sB[ci * 512]);
    }
    __syncthreads();
#pragma unroll
    for (int kk = 0; kk < 2; ++kk) {
      bf16x8 af[4], bfr[4];
#pragma unroll
      for (int mf = 0; mf < 4; ++mf)
        af[mf] = *(const bf16x8*)&sA[(wm * 64 + mf * 16 + fr) * 64 + kk * 32 + fq * 8];
#pragma unroll
      for (int nf = 0; nf < 4; ++nf)
        bfr[nf] = *(const bf16x8*)&sB[(wn * 64 + nf * 16 + fr) * 64 + kk * 32 + fq * 8];
#pragma unroll
      for (int mf = 0; mf < 4; ++mf)
#pragma unroll
        for (int nf = 0; nf < 4; ++nf)
          acc[mf][nf] = __builtin_amdgcn_mfma_f32_16x16x32_bf16(
              af[mf], bfr[nf], acc[mf][nf], 0, 0, 0);
    }
  }

#pragma unroll
  for (int mf = 0; mf < 4; ++mf)
#pragma unroll
    for (int nf = 0; nf < 4; ++nf) {
      int col = bn * 128 + wn * 64 + nf * 16 + fr;
#pragma unroll
      for (int j = 0; j < 4; ++j) {
        int row = bm * 128 + wm * 64 + mf * 16 + fq * 4 + j;
        C[(size_t)row * N + col] = f2b(acc[mf][nf][j]);
      }
    }
}

// ---------------- split-K variant (blockIdx.z = K-slice), partial outputs ----
__global__ __launch_bounds__(256)
void k_gemm_bt_split(const u16* __restrict__ A, const u16* __restrict__ Bt,
                     float* __restrict__ Cp, int M, int N, int K, int klen) {
  __shared__ u16 sA[128 * 64];
  __shared__ u16 sB[128 * 64];
  const int tid = threadIdx.x;
  const int wave = tid >> 6, lane = tid & 63;
  const int bn = blockIdx.x, bm = blockIdx.y, z = blockIdx.z;
  const int wm = wave >> 1, wn = wave & 1;
  const int fr = lane & 15, fq = lane >> 4;
  const int srow = lane >> 3;
  const int scol = (lane & 7) * 8;
  const int k0 = z * klen;
  float* C = Cp + (size_t)z * M * N;

  const u16* Ab = A + (size_t)bm * 128 * K;
  const u16* Bb = Bt + (size_t)bn * 128 * K;

  f32x4 acc[4][4];
#pragma unroll
  for (int i = 0; i < 4; ++i)
#pragma unroll
    for (int j = 0; j < 4; ++j) acc[i][j] = (f32x4){0.f, 0.f, 0.f, 0.f};

  for (int kt = k0; kt < k0 + klen; kt += 64) {
    __syncthreads();
#pragma unroll
    for (int i = 0; i < 4; ++i) {
      int ci = wave * 4 + i;
      int row = ci * 8 + srow;
      gl2lds16(Ab + (size_t)row * K + kt + scol, &sA[ci * 512]);
      gl2lds16(Bb + (size_t)row * K + kt + scol, &sB[ci * 512]);
    }
    __syncthreads();
#pragma unroll
    for (int kk = 0; kk < 2; ++kk) {
      bf16x8 af[4], bfr[4];
#pragma unroll
      for (int mf = 0; mf < 4; ++mf)
        af[mf] = *(const bf16x8*)&sA[(wm * 64 + mf * 16 + fr) * 64 + kk * 32 + fq * 8];
#pragma unroll
      for (int nf = 0; nf < 4; ++nf)
        bfr[nf] = *(const bf16x8*)&sB[(wn * 64 + nf * 16 + fr) * 64 + kk * 32 + fq * 8];
#pragma unroll
      for (int mf = 0; mf < 4; ++mf)
#pragma unroll
        for (int nf = 0; nf < 4; ++nf)
          acc[mf][nf] = __builtin_amdgcn_mfma_f32_16x16x32_bf16(
              af[mf], bfr[nf], acc[mf][nf], 0, 0, 0);
    }
  }

#pragma unroll
  for (int mf = 0; mf < 4; ++mf)
#pragma unroll
    for (int nf = 0; nf < 4; ++nf) {
      int col = bn * 128 + wn * 64 + nf * 16 + fr;
#pragma unroll
      for (int j = 0; j < 4; ++j) {
        int row = bm * 128 + wm * 64 + mf * 16 + fq * 4 + j;
        C[(size_t)row * N + col] = acc[mf][nf][j];
      }
    }
}

// -------- reduce split-K partials -> ssm fp32; fuse time_step bf16 extract ---
__global__ __launch_bounds__(256)
void k_xred(const float* __restrict__ Cp, float* __restrict__ ssm,
            u16* __restrict__ tsb) {
  int i = blockIdx.x * 256 + threadIdx.x;   // over L*NPAD/4
  int l = i >> 6, g = i & 63;
  f32x4 s = (f32x4){0.f, 0.f, 0.f, 0.f};
#pragma unroll
  for (int z = 0; z < KSP; ++z)
    s += *(const f32x4*)&Cp[(size_t)z * L_DIM * NPAD + (size_t)l * NPAD + g * 4];
  *(f32x4*)&ssm[(size_t)l * NPAD + g * 4] = s;
  if (g < 32) {
    ushort4 o;
    o.x = f2b(s[0]); o.y = f2b(s[1]); o.z = f2b(s[2]); o.w = f2b(s[3]);
    *(ushort4*)&tsb[(size_t)l * R_TS + g * 4] = o;
  }
}

// ---------------- depthwise causal conv (K=4) + bias + silu -> bf16 ---------
__global__ __launch_bounds__(256)
void k_conv_silu(const u16* __restrict__ Phid, const float* __restrict__ ck,
                 const float* __restrict__ cb, u16* __restrict__ hb) {
  int idx = blockIdx.x * 256 + threadIdx.x;       // over L*D/4
  int l = idx >> 10, d0 = (idx & 1023) * 4;       // D/4 = 1024
  float4 a = *(const float4*)&cb[d0];
#pragma unroll
  for (int k = 0; k < 4; ++k) {
    int ll = l - 3 + k;
    if (ll >= 0) {
      ushort4 pv = *(const ushort4*)&Phid[(size_t)ll * D_DIM + d0];
      a.x = fmaf(b2f(pv.x), ck[(d0 + 0) * 4 + k], a.x);
      a.y = fmaf(b2f(pv.y), ck[(d0 + 1) * 4 + k], a.y);
      a.z = fmaf(b2f(pv.z), ck[(d0 + 2) * 4 + k], a.z);
      a.w = fmaf(b2f(pv.w), ck[(d0 + 3) * 4 + k], a.w);
    }
  }
  ushort4 o;
  o.x = f2b(a.x / (1.f + __expf(-a.x)));
  o.y = f2b(a.y / (1.f + __expf(-a.y)));
  o.z = f2b(a.z / (1.f + __expf(-a.z)));
  o.w = f2b(a.w / (1.f + __expf(-a.w)));
  *(ushort4*)&hb[(size_t)l * D_DIM + d0] = o;
}

// ---------------- chunked selective scan (NC=64, CL=32) ----------------
__global__ __launch_bounds__(256)
void k_scan_partial(const u16* __restrict__ dtraw, const float* __restrict__ b_dt,
                    const u16* __restrict__ hb, const float* __restrict__ ssm,
                    const float* __restrict__ A_log, float* __restrict__ sC,
                    float* __restrict__ aP) {
  __shared__ float sBl[CL][16];
  const int c = blockIdx.x >> 4;
  const int d = ((blockIdx.x & 15) << 8) + threadIdx.x;
  const int l0 = c * CL;
  {
    int t = threadIdx.x;
    if (t < CL * 4) {
      int r = t >> 2, j = (t & 3) * 4;
      *(float4*)&sBl[r][j] =
          *(const float4*)&ssm[(size_t)(l0 + r) * NPAD + R_TS + j];
    }
  }
  float Ac[N_ST];
#pragma unroll
  for (int n = 0; n < N_ST; ++n) Ac[n] = -__expf(A_log[d * N_ST + n]);
  const float bdt = b_dt[d];
  float s[N_ST], ap[N_ST];
#pragma unroll
  for (int n = 0; n < N_ST; ++n) { s[n] = 0.f; ap[n] = 1.f; }
  __syncthreads();

  float dtn = b2f(dtraw[(size_t)l0 * D_DIM + d]);
  float hn = b2f(hb[(size_t)l0 * D_DIM + d]);
  for (int i = 0; i < CL; ++i) {
    const float x = dtn + bdt;
    const float hv = hn;
    const int ip = (i + 1 < CL) ? (i + 1) : i;
    dtn = b2f(dtraw[(size_t)(l0 + ip) * D_DIM + d]);
    hn = b2f(hb[(size_t)(l0 + ip) * D_DIM + d]);
    const float dt = (x > 20.f) ? x : __logf(1.f + __expf(x));
    const float dth = dt * hv;
#pragma unroll
    for (int n = 0; n < N_ST; ++n) {
      float dA = __expf(Ac[n] * dt);
      s[n] = fmaf(dA, s[n], dth * sBl[i][n]);
      ap[n] *= dA;
    }
  }
  float* so = sC + ((size_t)c * D_DIM + d) * N_ST;
  float* ao = aP + ((size_t)c * D_DIM + d) * N_ST;
#pragma unroll
  for (int n = 0; n < N_ST; ++n) { so[n] = s[n]; ao[n] = ap[n]; }
}

__global__ __launch_bounds__(256)
void k_scan_combine(const float* __restrict__ sC, const float* __restrict__ aP,
                    float* __restrict__ init) {
  const int i = blockIdx.x * 256 + threadIdx.x;
  float s = 0.f;
  for (int c = 0; c < NC; ++c) {
    init[(size_t)c * (D_DIM * N_ST) + i] = s;
    s = fmaf(aP[(size_t)c * (D_DIM * N_ST) + i], s,
             sC[(size_t)c * (D_DIM * N_ST) + i]);
  }
}

__global__ __launch_bounds__(256)
void k_scan_final(const u16* __restrict__ dtraw, const float* __restrict__ b_dt,
                  const u16* __restrict__ hb, const float* __restrict__ ssm,
                  const float* __restrict__ A_log, const float* __restrict__ init,
                  const u16* __restrict__ Pgate, const float* __restrict__ Dp,
                  u16* __restrict__ yb) {
  __shared__ float sBC[CL][32];
  const int c = blockIdx.x >> 4;
  const int d = ((blockIdx.x & 15) << 8) + threadIdx.x;
  const int l0 = c * CL;
  {
    int t = threadIdx.x;
    if (t < CL * 8) {
      int r = t >> 3, j = (t & 7) * 4;
      *(float4*)&sBC[r][j] =
          *(const float4*)&ssm[(size_t)(l0 + r) * NPAD + R_TS + j];
    }
  }
  float Ac[N_ST];
#pragma unroll
  for (int n = 0; n < N_ST; ++n) Ac[n] = -__expf(A_log[d * N_ST + n]);
  const float bdt = b_dt[d], dpd = Dp[d];
  float s[N_ST];
  const float* ini = init + ((size_t)c * D_DIM + d) * N_ST;
#pragma unroll
  for (int n = 0; n < N_ST; ++n) s[n] = ini[n];
  __syncthreads();

  float dtn = b2f(dtraw[(size_t)l0 * D_DIM + d]);
  float hn = b2f(hb[(size_t)l0 * D_DIM + d]);
  float gn = b2f(Pgate[(size_t)l0 * D_DIM + d]);
  for (int i = 0; i < CL; ++i) {
    const float x = dtn + bdt;
    const float hv = hn;
    const float gv = gn;
    const int ip = (i + 1 < CL) ? (i + 1) : i;
    dtn = b2f(dtraw[(size_t)(l0 + ip) * D_DIM + d]);
    hn = b2f(hb[(size_t)(l0 + ip) * D_DIM + d]);
    gn = b2f(Pgate[(size_t)(l0 + ip) * D_DIM + d]);
    const float dt = (x > 20.f) ? x : __logf(1.f + __expf(x));
    const float dth = dt * hv;
    float y = 0.f;
#pragma unroll
    for (int n = 0; n < N_ST; ++n) {
      float dA = __expf(Ac[n] * dt);
      s[n] = fmaf(dA, s[n], dth * sBC[i][n]);
      y = fmaf(s[n], sBC[i][16 + n], y);
    }
    y = fmaf(hv, dpd, y);
    const float sg = gv / (1.f + __expf(-gv));
    yb[(size_t)(l0 + i) * D_DIM + d] = f2b(y * sg);
  }
}

// ---------------- launcher ----------------
extern "C" void kernel_launch(void* const* d_in, const int* in_sizes, int n_in,
                              void* d_out, int out_size, void* d_ws, size_t ws_size,
                              hipStream_t stream) {
  const float* X     = (const float*)d_in[0];
  const float* W_in  = (const float*)d_in[1];
  const float* ck    = (const float*)d_in[2];
  const float* cb    = (const float*)d_in[3];
  const float* W_x   = (const float*)d_in[4];
  const float* W_dt  = (const float*)d_in[5];
  const float* b_dt  = (const float*)d_in[6];
  const float* W_out = (const float*)d_in[7];
  const float* A_log = (const float*)d_in[8];
  const float* Dp    = (const float*)d_in[9];

  char* w = (char*)d_ws;
  size_t off = 0;
  auto alloc = [&](size_t bytes) {
    void* p = w + off;
    off = (off + bytes + 255) & ~(size_t)255;
    return p;
  };
  u16*   Xb    = (u16*)  alloc((size_t)L_DIM * H_DIM * 2);        //  0.0 -  8.4 MB
  u16*   WinT  = (u16*)  alloc((size_t)2 * D_DIM * H_DIM * 2);    //  8.4 - 42.0
  u16*   Phid  = (u16*)  alloc((size_t)L_DIM * D_DIM * 2);        // 42.0 - 58.8
  u16*   Pgate = (u16*)  alloc((size_t)L_DIM * D_DIM * 2);        // 58.8 - 75.6
  u16*   hb    = (u16*)  alloc((size_t)L_DIM * D_DIM * 2);        // 75.6 - 92.4
  u16*   WxT   = (u16*)  alloc((size_t)NPAD * D_DIM * 2);
  float* ssm   = (float*)alloc((size_t)L_DIM * NPAD * 4);
  u16*   tsb   = (u16*)  alloc((size_t)L_DIM * R_TS * 2);
  u16*   WdtT  = (u16*)  alloc((size_t)D_DIM * R_TS * 2);
  u16*   dtraw = (u16*)  alloc((size_t)L_DIM * D_DIM * 2);        // bf16
  u16*   WoutT = (u16*)  alloc((size_t)H_DIM * D_DIM * 2);
  u16*   yb    = (u16*)  alloc((size_t)L_DIM * D_DIM * 2);        // ~149 MB linear
  // Aliases (disjoint lifetimes, round-5-proven layout):
  //  xpart (16.8 MB, steps 6-7)       @0      (Xb+WinT dead after step 3)
  //  sCb/aPb (2x16.8 MB, steps 10-11) @0/16.8 (same dead region)
  //  initb (16.8 MB, steps 11-12)     @Phid   (dead after step 4; exact fit)
  //  opartb bf16 (33.6 MB, steps 14-15) @0    (Xb+WinT region, dead by 14)
  float* xpart  = (float*)d_ws;
  float* sCb    = (float*)d_ws;
  float* aPb    = (float*)((char*)d_ws + (size_t)NC * D_DIM * N_ST * 4);
  float* initb  = (float*)Phid;
  u16*   opartb = (u16*)d_ws;
  (void)ws_size;

  // 1) X -> bf16
  k_f32_to_bf16<<<(L_DIM * H_DIM / 4 + 255) / 256, 256, 0, stream>>>(
      X, Xb, L_DIM * H_DIM / 4);
  // 2) W_in [H,2D] -> WinT [2D,H]
  k_transpose_bf16<<<dim3(2 * D_DIM / 32, H_DIM / 32), dim3(32, 8), 0, stream>>>(
      W_in, WinT, H_DIM, 2 * D_DIM);
  // 3) {Phid|Pgate} = X * W_in   (8-phase 256^2, bf16 outputs)
  k_gemm256<<<dim3(2 * D_DIM / 256, L_DIM / 256), 512, 0, stream>>>(
      Xb, WinT, Phid, Pgate, L_DIM, 2 * D_DIM, H_DIM, D_DIM);
  // 4) conv + silu -> hb (bf16), 4-wide vectorized
  k_conv_silu<<<L_DIM * D_DIM / 4 / 256, 256, 0, stream>>>(Phid, ck, cb, hb);
  // 5) W_x [D,160] -> WxT [256,D] zero-padded
  k_transpose_bf16<<<dim3(NPAD / 32, D_DIM / 32), dim3(32, 8), 0, stream>>>(
      W_x, WxT, D_DIM, R_TS + 2 * N_ST);
  // 6-7) ssm partials = h * W_x  (split-K=8), reduce + ts extract
  k_gemm_bt_split<<<dim3(NPAD / 128, L_DIM / 128, KSP), 256, 0, stream>>>(
      hb, WxT, xpart, L_DIM, NPAD, D_DIM, D_DIM / KSP);
  k_xred<<<L_DIM * NPAD / 4 / 256, 256, 0, stream>>>(xpart, ssm, tsb);
  // 8) W_dt [128,D] -> WdtT [D,128]
  k_transpose_bf16<<<dim3(D_DIM / 32, R_TS / 32), dim3(32, 8), 0, stream>>>(
      W_dt, WdtT, R_TS, D_DIM);
  // 9) dtraw = ts * W_dt  [L, D] (bf16 out)
  k_gemm_bt16<<<dim3(D_DIM / 128, L_DIM / 128), 256, 0, stream>>>(
      tsb, WdtT, dtraw, L_DIM, D_DIM, R_TS);
  // 10-12) chunked scan (NC=64 chunks of CL=32)
  k_scan_partial<<<NC * (D_DIM / 256), 256, 0, stream>>>(
      dtraw, b_dt, hb, ssm, A_log, sCb, aPb);
  k_scan_combine<<<D_DIM * N_ST / 256, 256, 0, stream>>>(sCb, aPb, initb);
  k_scan_final<<<NC * (D_DIM / 256), 256, 0, stream>>>(
      dtraw, b_dt, hb, ssm, A_log, initb, Pgate, Dp, yb);
  // 13) W_out [D,H] -> WoutT [H,D]
  k_transpose_bf16<<<dim3(H_DIM / 32, D_DIM / 32), dim3(32, 8), 0, stream>>>(
      W_out, WoutT, D_DIM, H_DIM);
  // 14-15) out = y * W_out  (8-phase 256^2, split-K=4, bf16 partials) + reduce
  k_gemm256s<<<dim3(H_DIM / 256, L_DIM / 256, KSPO), 512, 0, stream>>>(
      yb, WoutT, opartb, L_DIM, H_DIM, D_DIM, D_DIM / KSPO);
  k_ored<<<L_DIM * H_DIM / 4 / 256, 256, 0, stream>>>(opartb, (float*)d_out);
}

// Round 10
// 318.251 us; speedup vs baseline: 1.1028x; 1.0656x over previous
//
#include <hip/hip_runtime.h>

// Problem dims
#define L_DIM 2048
#define H_DIM 2048
#define D_DIM 4096
#define N_ST  16
#define R_TS  128
#define NPAD  256   // padded R+2N (160 -> 256)
#define NC    64    // scan chunks (64 proven best: 128 regressed, r8)
#define CL    32    // steps per chunk (NC*CL = L)
#define KSP   8     // split-K factor for x_proj
#define KSPO  4     // split-K factor for out_proj

typedef unsigned short u16;
typedef short bf16x8 __attribute__((ext_vector_type(8)));
typedef float f32x4 __attribute__((ext_vector_type(4)));

__device__ __forceinline__ u16 f2b(float x) {
  union { float f; unsigned u; } v; v.f = x;
  unsigned r = v.u + 0x7fffu + ((v.u >> 16) & 1u);
  return (u16)(r >> 16);
}
__device__ __forceinline__ float b2f(u16 v) {
  union { unsigned u; float f; } x; x.u = (unsigned)v << 16; return x.f;
}

__device__ __forceinline__ void gl2lds16(const u16* g, u16* l) {
  __builtin_amdgcn_global_load_lds(
      (const __attribute__((address_space(1))) unsigned*)g,
      (__attribute__((address_space(3))) unsigned*)l, 16, 0, 0);
}

// ---------------- straight fp32 -> bf16 convert (vectorized) ----------------
__global__ __launch_bounds__(256)
void k_f32_to_bf16(const float* __restrict__ s, u16* __restrict__ d, int n4) {
  int i = blockIdx.x * 256 + threadIdx.x;
  if (i >= n4) return;
  float4 v = ((const float4*)s)[i];
  ushort4 o;
  o.x = f2b(v.x); o.y = f2b(v.y); o.z = f2b(v.z); o.w = f2b(v.w);
  ((ushort4*)d)[i] = o;
}

// ---------------- tiled transpose fp32 [R,C] -> bf16 [Cp,R], zero-pad C..Cp --
__global__ __launch_bounds__(256)
void k_transpose_bf16(const float* __restrict__ src, u16* __restrict__ dst,
                      int R, int C) {
  __shared__ float t[32][33];
  const int x = threadIdx.x, y = threadIdx.y;     // 32 x 8
  const int c0 = blockIdx.x * 32, r0 = blockIdx.y * 32;
#pragma unroll
  for (int i = 0; i < 4; ++i) {
    int r = r0 + y + i * 8, c = c0 + x;
    t[y + i * 8][x] = (c < C) ? src[(size_t)r * C + c] : 0.f;
  }
  __syncthreads();
#pragma unroll
  for (int i = 0; i < 4; ++i) {
    int cc = c0 + y + i * 8;
    dst[(size_t)cc * R + r0 + x] = f2b(t[x][y + i * 8]);
  }
}

// ============ 256x256 8-phase bf16 MFMA GEMM: C = A[M,K] * Bt[N,K]^T ========
// Output split into two bf16 [M, NS] buffers (cols < NS -> C0, else C1).
// No XCD swizzle: with gridDim.x=32 the linear mapping gives XCD = bn%8
// (B-panel per-XCD L2 locality); r7 swizzle tripled FETCH (143 MB) for 0 gain.
__global__ __launch_bounds__(512, 2)
void k_gemm256(const u16* __restrict__ A, const u16* __restrict__ Bt,
               u16* __restrict__ C0, u16* __restrict__ C1,
               int M, int N, int K, int NS) {
  __shared__ u16 lA[2][256][64];
  __shared__ u16 lB[2][256][64];
  const int tid = threadIdx.x;
  const int w = tid >> 6, lane = tid & 63;
  const int wm = w >> 2, wn = w & 3;          // 2 x 4 waves
  const int fr = lane & 15, fq = lane >> 4;
  const int xr = (fr & 7) << 4;               // read-side XOR (bytes)
  const int sr = lane >> 3;                   // stage row-in-group 0..7
  const int sc = ((lane & 7) ^ sr) << 3;      // stage source col (elems), pre-swizzled
  const int bn = blockIdx.x, bm = blockIdx.y;
  const u16* Ag = A + (size_t)bm * 256 * K;
  const u16* Bg = Bt + (size_t)bn * 256 * K;
  const int NT = K >> 6;

  f32x4 acc[8][4];
#pragma unroll
  for (int i = 0; i < 8; ++i)
#pragma unroll
    for (int j = 0; j < 4; ++j) acc[i][j] = (f32x4){0.f, 0.f, 0.f, 0.f};

  bf16x8 af[4][2];
  bf16x8 bfr[4][2];

#define STAGE_HALF(LT, G, TT, H) do {                                   \
    const int b_ = (TT) & 1; const int kt_ = (TT) << 6;                 \
    const u16* g0_ = (G) + (size_t)((H) * 128 + w * 8 + sr) * K + kt_ + sc; \
    u16* l0_ = &LT[b_][(H) * 128 + w * 8][0];                           \
    gl2lds16(g0_, l0_);                                                 \
    gl2lds16(g0_ + (size_t)64 * K, l0_ + 64 * 64);                      \
  } while (0)

#define LDA_HALF(BB, MH) do {                                           \
    const char* bA_ = (const char*)lA + (size_t)(BB) * 32768;           \
    _Pragma("unroll")                                                   \
    for (int m_ = 0; m_ < 4; ++m_) {                                    \
      const char* rp_ = bA_ + (wm * 128 + (MH) * 64 + m_ * 16 + fr) * 128; \
      af[m_][0] = *(const bf16x8*)(rp_ + ((fq << 4) ^ xr));             \
      af[m_][1] = *(const bf16x8*)(rp_ + ((64 | (fq << 4)) ^ xr));      \
    } } while (0)

#define LDB_HALF(BB, NH) do {                                           \
    const char* bB_ = (const char*)lB + (size_t)(BB) * 32768;           \
    _Pragma("unroll")                                                   \
    for (int n_ = 0; n_ < 2; ++n_) {                                    \
      const char* rp_ = bB_ + (wn * 64 + ((NH) * 2 + n_) * 16 + fr) * 128; \
      bfr[(NH) * 2 + n_][0] = *(const bf16x8*)(rp_ + ((fq << 4) ^ xr)); \
      bfr[(NH) * 2 + n_][1] = *(const bf16x8*)(rp_ + ((64 | (fq << 4)) ^ xr)); \
    } } while (0)

#define MFMA_Q(MH, NH) do {                                             \
    __builtin_amdgcn_s_setprio(1);                                      \
    _Pragma("unroll")                                                   \
    for (int m_ = 0; m_ < 4; ++m_)                                      \
      _Pragma("unroll")                                                 \
      for (int n_ = 0; n_ < 2; ++n_) {                                  \
        acc[(MH)*4+m_][(NH)*2+n_] = __builtin_amdgcn_mfma_f32_16x16x32_bf16( \
            af[m_][0], bfr[(NH)*2+n_][0], acc[(MH)*4+m_][(NH)*2+n_], 0, 0, 0); \
        acc[(MH)*4+m_][(NH)*2+n_] = __builtin_amdgcn_mfma_f32_16x16x32_bf16( \
            af[m_][1], bfr[(NH)*2+n_][1], acc[(MH)*4+m_][(NH)*2+n_], 0, 0, 0); \
      }                                                                 \
    __builtin_amdgcn_s_setprio(0);                                      \
  } while (0)

#define BAR() __builtin_amdgcn_s_barrier()
#define LGKM0() do { asm volatile("s_waitcnt lgkmcnt(0)" ::: "memory"); \
                     __builtin_amdgcn_sched_barrier(0); } while (0)

  STAGE_HALF(lA, Ag, 0, 0); STAGE_HALF(lA, Ag, 0, 1);
  STAGE_HALF(lB, Bg, 0, 0); STAGE_HALF(lB, Bg, 0, 1);
  STAGE_HALF(lB, Bg, 1, 0); STAGE_HALF(lB, Bg, 1, 1);
  asm volatile("s_waitcnt vmcnt(4)" ::: "memory");
  BAR();

  for (int t = 0; t < NT; ++t) {
    const int b = t & 1;
    const int ta = (t + 1 == NT) ? 0 : t + 1;
    const int tb = (t + 2 >= NT) ? (t + 2 - NT) : t + 2;
    LDA_HALF(b, 0); LDB_HALF(b, 0);
    STAGE_HALF(lA, Ag, ta, 0);
    BAR(); LGKM0();
    MFMA_Q(0, 0);
    BAR();
    LDB_HALF(b, 1);
    STAGE_HALF(lA, Ag, ta, 1);
    BAR(); LGKM0();
    MFMA_Q(0, 1);
    BAR();
    LDA_HALF(b, 1);
    STAGE_HALF(lB, Bg, tb, 0);
    BAR(); LGKM0();
    MFMA_Q(1, 0);
    BAR();
    STAGE_HALF(lB, Bg, tb, 1);
    BAR(); LGKM0();
    MFMA_Q(1, 1);
    asm volatile("s_waitcnt vmcnt(4)" ::: "memory");
    BAR();
  }
  asm volatile("s_waitcnt vmcnt(0)" ::: "memory");

#pragma unroll
  for (int mi = 0; mi < 8; ++mi)
#pragma unroll
    for (int n = 0; n < 4; ++n) {
      int col = bn * 256 + wn * 64 + n * 16 + fr;
      u16* Cd = C0;
      if (col >= NS) { Cd = C1; col -= NS; }
      const int row0 = bm * 256 + wm * 128 + mi * 16 + fq * 4;
#pragma unroll
      for (int j = 0; j < 4; ++j)
        Cd[(size_t)(row0 + j) * NS + col] = f2b(acc[mi][n][j]);
    }
}

// ===== split-K 8-phase 256^2 kernel: bf16 partials per z =====
// (r5/r6 measured: partial stores + separate reduce >> atomicAdd epilogue)
__global__ __launch_bounds__(512, 2)
void k_gemm256s(const u16* __restrict__ A, const u16* __restrict__ Bt,
                u16* __restrict__ Cp, int M, int N, int K, int klen) {
  __shared__ u16 lA[2][256][64];
  __shared__ u16 lB[2][256][64];
  const int tid = threadIdx.x;
  const int w = tid >> 6, lane = tid & 63;
  const int wm = w >> 2, wn = w & 3;
  const int fr = lane & 15, fq = lane >> 4;
  const int xr = (fr & 7) << 4;
  const int sr = lane >> 3;
  const int sc = ((lane & 7) ^ sr) << 3;
  const int bn = blockIdx.x, bm = blockIdx.y, z = blockIdx.z;
  const int k0 = z * klen;
  const u16* Ag = A + (size_t)bm * 256 * K;
  const u16* Bg = Bt + (size_t)bn * 256 * K;
  const int NT = klen >> 6;
  u16* C = Cp + (size_t)z * M * N;

  f32x4 acc[8][4];
#pragma unroll
  for (int i = 0; i < 8; ++i)
#pragma unroll
    for (int j = 0; j < 4; ++j) acc[i][j] = (f32x4){0.f, 0.f, 0.f, 0.f};

  bf16x8 af[4][2];
  bf16x8 bfr[4][2];

#undef STAGE_HALF
#define STAGE_HALF(LT, G, TT, H) do {                                   \
    const int b_ = (TT) & 1; const int kt_ = ((TT) << 6) + k0;          \
    const u16* g0_ = (G) + (size_t)((H) * 128 + w * 8 + sr) * K + kt_ + sc; \
    u16* l0_ = &LT[b_][(H) * 128 + w * 8][0];                           \
    gl2lds16(g0_, l0_);                                                 \
    gl2lds16(g0_ + (size_t)64 * K, l0_ + 64 * 64);                      \
  } while (0)

  STAGE_HALF(lA, Ag, 0, 0); STAGE_HALF(lA, Ag, 0, 1);
  STAGE_HALF(lB, Bg, 0, 0); STAGE_HALF(lB, Bg, 0, 1);
  STAGE_HALF(lB, Bg, 1, 0); STAGE_HALF(lB, Bg, 1, 1);
  asm volatile("s_waitcnt vmcnt(4)" ::: "memory");
  BAR();

  for (int t = 0; t < NT; ++t) {
    const int b = t & 1;
    const int ta = (t + 1 == NT) ? 0 : t + 1;
    const int tb = (t + 2 >= NT) ? (t + 2 - NT) : t + 2;
    LDA_HALF(b, 0); LDB_HALF(b, 0);
    STAGE_HALF(lA, Ag, ta, 0);
    BAR(); LGKM0();
    MFMA_Q(0, 0);
    BAR();
    LDB_HALF(b, 1);
    STAGE_HALF(lA, Ag, ta, 1);
    BAR(); LGKM0();
    MFMA_Q(0, 1);
    BAR();
    LDA_HALF(b, 1);
    STAGE_HALF(lB, Bg, tb, 0);
    BAR(); LGKM0();
    MFMA_Q(1, 0);
    BAR();
    STAGE_HALF(lB, Bg, tb, 1);
    BAR(); LGKM0();
    MFMA_Q(1, 1);
    asm volatile("s_waitcnt vmcnt(4)" ::: "memory");
    BAR();
  }
  asm volatile("s_waitcnt vmcnt(0)" ::: "memory");

#undef STAGE_HALF
#undef LDA_HALF
#undef LDB_HALF
#undef MFMA_Q
#undef BAR
#undef LGKM0

#pragma unroll
  for (int mi = 0; mi < 8; ++mi)
#pragma unroll
    for (int n = 0; n < 4; ++n) {
      const int col = bn * 256 + wn * 64 + n * 16 + fr;
      const int row0 = bm * 256 + wm * 128 + mi * 16 + fq * 4;
#pragma unroll
      for (int j = 0; j < 4; ++j)
        C[(size_t)(row0 + j) * N + col] = f2b(acc[mi][n][j]);
    }
}

// -------- reduce out_proj bf16 split-K partials -> fp32 output --------------
__global__ __launch_bounds__(256)
void k_ored(const u16* __restrict__ Cp, float* __restrict__ out) {
  const int i = blockIdx.x * 256 + threadIdx.x;   // over M*N/4
  f32x4 s = (f32x4){0.f, 0.f, 0.f, 0.f};
#pragma unroll
  for (int z = 0; z < KSPO; ++z) {
    ushort4 p = *(const ushort4*)&Cp[(size_t)z * L_DIM * H_DIM + (size_t)i * 4];
    s[0] += b2f(p.x); s[1] += b2f(p.y); s[2] += b2f(p.z); s[3] += b2f(p.w);
  }
  *(f32x4*)&out[(size_t)i * 4] = s;
}

// ---------------- bf16 MFMA GEMM (128x128, m97-style): C = A * Bt^T ---------
// fp32-output variant (dt_proj; r10 restored -- bf16 dtraw regressed ~20us,
// r5 vs r7/r8/r9 ledger)
__global__ __launch_bounds__(256)
void k_gemm_bt(const u16* __restrict__ A, const u16* __restrict__ Bt,
               float* __restrict__ C, int M, int N, int K) {
  __shared__ u16 sA[128 * 64];
  __shared__ u16 sB[128 * 64];
  const int tid = threadIdx.x;
  const int wave = tid >> 6, lane = tid & 63;
  const int bn = blockIdx.x, bm = blockIdx.y;
  const int wm = wave >> 1, wn = wave & 1;
  const int fr = lane & 15, fq = lane >> 4;
  const int srow = lane >> 3;
  const int scol = (lane & 7) * 8;

  const u16* Ab = A + (size_t)bm * 128 * K;
  const u16* Bb = Bt + (size_t)bn * 128 * K;

  f32x4 acc[4][4];
#pragma unroll
  for (int i = 0; i < 4; ++i)
#pragma unroll
    for (int j = 0; j < 4; ++j) acc[i][j] = (f32x4){0.f, 0.f, 0.f, 0.f};

  for (int kt = 0; kt < K; kt += 64) {
    __syncthreads();
#pragma unroll
    for (int i = 0; i < 4; ++i) {
      int ci = wave * 4 + i;
      int row = ci * 8 + srow;
      gl2lds16(Ab + (size_t)row * K + kt + scol, &sA[ci * 512]);
      gl2lds16(Bb + (size_t)row * K + kt + scol, &sB[ci * 512]);
    }
    __syncthreads();
#pragma unroll
    for (int kk = 0; kk < 2; ++kk) {
      bf16x8 af[4], bfr[4];
#pragma unroll
      for (int mf = 0; mf < 4; ++mf)
        af[mf] = *(const bf16x8*)&sA[(wm * 64 + mf * 16 + fr) * 64 + kk * 32 + fq * 8];
#pragma unroll
      for (int nf = 0; nf < 4; ++nf)
        bfr[nf] = *(const bf16x8*)&sB[(wn * 64 + nf * 16 + fr) * 64 + kk * 32 + fq * 8];
#pragma unroll
      for (int mf = 0; mf < 4; ++mf)
#pragma unroll
        for (int nf = 0; nf < 4; ++nf)
          acc[mf][nf] = __builtin_amdgcn_mfma_f32_16x16x32_bf16(
              af[mf], bfr[nf], acc[mf][nf], 0, 0, 0);
    }
  }

#pragma unroll
  for (int mf = 0; mf < 4; ++mf)
#pragma unroll
    for (int nf = 0; nf < 4; ++nf) {
      int col = bn * 128 + wn * 64 + nf * 16 + fr;
#pragma unroll
      for (int j = 0; j < 4; ++j) {
        int row = bm * 128 + wm * 64 + mf * 16 + fq * 4 + j;
        C[(size_t)row * N + col] = acc[mf][nf][j];
      }
    }
}

// ---------------- split-K variant (blockIdx.z = K-slice), partial outputs ----
__global__ __launch_bounds__(256)
void k_gemm_bt_split(const u16* __restrict__ A, const u16* __restrict__ Bt,
                     float* __restrict__ Cp, int M, int N, int K, int klen) {
  __shared__ u16 sA[128 * 64];
  __shared__ u16 sB[128 * 64];
  const int tid = threadIdx.x;
  const int wave = tid >> 6, lane = tid & 63;
  const int bn = blockIdx.x, bm = blockIdx.y, z = blockIdx.z;
  const int wm = wave >> 1, wn = wave & 1;
  const int fr = lane & 15, fq = lane >> 4;
  const int srow = lane >> 3;
  const int scol = (lane & 7) * 8;
  const int k0 = z * klen;
  float* C = Cp + (size_t)z * M * N;

  const u16* Ab = A + (size_t)bm * 128 * K;
  const u16* Bb = Bt + (size_t)bn * 128 * K;

  f32x4 acc[4][4];
#pragma unroll
  for (int i = 0; i < 4; ++i)
#pragma unroll
    for (int j = 0; j < 4; ++j) acc[i][j] = (f32x4){0.f, 0.f, 0.f, 0.f};

  for (int kt = k0; kt < k0 + klen; kt += 64) {
    __syncthreads();
#pragma unroll
    for (int i = 0; i < 4; ++i) {
      int ci = wave * 4 + i;
      int row = ci * 8 + srow;
      gl2lds16(Ab + (size_t)row * K + kt + scol, &sA[ci * 512]);
      gl2lds16(Bb + (size_t)row * K + kt + scol, &sB[ci * 512]);
    }
    __syncthreads();
#pragma unroll
    for (int kk = 0; kk < 2; ++kk) {
      bf16x8 af[4], bfr[4];
#pragma unroll
      for (int mf = 0; mf < 4; ++mf)
        af[mf] = *(const bf16x8*)&sA[(wm * 64 + mf * 16 + fr) * 64 + kk * 32 + fq * 8];
#pragma unroll
      for (int nf = 0; nf < 4; ++nf)
        bfr[nf] = *(const bf16x8*)&sB[(wn * 64 + nf * 16 + fr) * 64 + kk * 32 + fq * 8];
#pragma unroll
      for (int mf = 0; mf < 4; ++mf)
#pragma unroll
        for (int nf = 0; nf < 4; ++nf)
          acc[mf][nf] = __builtin_amdgcn_mfma_f32_16x16x32_bf16(
              af[mf], bfr[nf], acc[mf][nf], 0, 0, 0);
    }
  }

#pragma unroll
  for (int mf = 0; mf < 4; ++mf)
#pragma unroll
    for (int nf = 0; nf < 4; ++nf) {
      int col = bn * 128 + wn * 64 + nf * 16 + fr;
#pragma unroll
      for (int j = 0; j < 4; ++j) {
        int row = bm * 128 + wm * 64 + mf * 16 + fq * 4 + j;
        C[(size_t)row * N + col] = acc[mf][nf][j];
      }
    }
}

// -------- reduce split-K partials -> ssm fp32; fuse time_step bf16 extract ---
__global__ __launch_bounds__(256)
void k_xred(const float* __restrict__ Cp, float* __restrict__ ssm,
            u16* __restrict__ tsb) {
  int i = blockIdx.x * 256 + threadIdx.x;   // over L*NPAD/4
  int l = i >> 6, g = i & 63;
  f32x4 s = (f32x4){0.f, 0.f, 0.f, 0.f};
#pragma unroll
  for (int z = 0; z < KSP; ++z)
    s += *(const f32x4*)&Cp[(size_t)z * L_DIM * NPAD + (size_t)l * NPAD + g * 4];
  *(f32x4*)&ssm[(size_t)l * NPAD + g * 4] = s;
  if (g < 32) {
    ushort4 o;
    o.x = f2b(s[0]); o.y = f2b(s[1]); o.z = f2b(s[2]); o.w = f2b(s[3]);
    *(ushort4*)&tsb[(size_t)l * R_TS + g * 4] = o;
  }
}

// ---------------- depthwise causal conv (K=4) + bias + silu -> bf16 ---------
// scalar r5-proven form (r6 vectorized variant implicated in ~20us regression)
__global__ __launch_bounds__(256)
void k_conv_silu(const u16* __restrict__ Phid, const float* __restrict__ ck,
                 const float* __restrict__ cb, u16* __restrict__ hb) {
  int idx = blockIdx.x * 256 + threadIdx.x;       // l*D + d
  int l = idx >> 12, d = idx & (D_DIM - 1);
  float acc = cb[d];
#pragma unroll
  for (int k = 0; k < 4; ++k) {
    int ll = l - 3 + k;
    if (ll >= 0) acc = fmaf(b2f(Phid[(size_t)ll * D_DIM + d]), ck[d * 4 + k], acc);
  }
  float sv = acc / (1.f + __expf(-acc));
  hb[idx] = f2b(sv);
}

// ---------------- chunked selective scan (NC=64, CL=32) ----------------
__global__ __launch_bounds__(256)
void k_scan_partial(const float* __restrict__ dtraw, const float* __restrict__ b_dt,
                    const u16* __restrict__ hb, const float* __restrict__ ssm,
                    const float* __restrict__ A_log, float* __restrict__ sC,
                    float* __restrict__ aP) {
  __shared__ float sBl[CL][16];
  const int c = blockIdx.x >> 4;
  const int d = ((blockIdx.x & 15) << 8) + threadIdx.x;
  const int l0 = c * CL;
  {
    int t = threadIdx.x;
    if (t < CL * 4) {
      int r = t >> 2, j = (t & 3) * 4;
      *(float4*)&sBl[r][j] =
          *(const float4*)&ssm[(size_t)(l0 + r) * NPAD + R_TS + j];
    }
  }
  float Ac[N_ST];
#pragma unroll
  for (int n = 0; n < N_ST; ++n) Ac[n] = -__expf(A_log[d * N_ST + n]);
  const float bdt = b_dt[d];
  float s[N_ST], ap[N_ST];
#pragma unroll
  for (int n = 0; n < N_ST; ++n) { s[n] = 0.f; ap[n] = 1.f; }
  __syncthreads();

  float dtn = dtraw[(size_t)l0 * D_DIM + d];
  float hn = b2f(hb[(size_t)l0 * D_DIM + d]);
  for (int i = 0; i < CL; ++i) {
    const float x = dtn + bdt;
    const float hv = hn;
    const int ip = (i + 1 < CL) ? (i + 1) : i;
    dtn = dtraw[(size_t)(l0 + ip) * D_DIM + d];
    hn = b2f(hb[(size_t)(l0 + ip) * D_DIM + d]);
    const float dt = (x > 20.f) ? x : __logf(1.f + __expf(x));
    const float dth = dt * hv;
#pragma unroll
    for (int n = 0; n < N_ST; ++n) {
      float dA = __expf(Ac[n] * dt);
      s[n] = fmaf(dA, s[n], dth * sBl[i][n]);
      ap[n] *= dA;
    }
  }
  float* so = sC + ((size_t)c * D_DIM + d) * N_ST;
  float* ao = aP + ((size_t)c * D_DIM + d) * N_ST;
#pragma unroll
  for (int n = 0; n < N_ST; ++n) { so[n] = s[n]; ao[n] = ap[n]; }
}

__global__ __launch_bounds__(256)
void k_scan_combine(const float* __restrict__ sC, const float* __restrict__ aP,
                    float* __restrict__ init) {
  const int i = blockIdx.x * 256 + threadIdx.x;
  float s = 0.f;
  for (int c = 0; c < NC; ++c) {
    init[(size_t)c * (D_DIM * N_ST) + i] = s;
    s = fmaf(aP[(size_t)c * (D_DIM * N_ST) + i], s,
             sC[(size_t)c * (D_DIM * N_ST) + i]);
  }
}

__global__ __launch_bounds__(256)
void k_scan_final(const float* __restrict__ dtraw, const float* __restrict__ b_dt,
                  const u16* __restrict__ hb, const float* __restrict__ ssm,
                  const float* __restrict__ A_log, const float* __restrict__ init,
                  const u16* __restrict__ Pgate, const float* __restrict__ Dp,
                  u16* __restrict__ yb) {
  __shared__ float sBC[CL][32];
  const int c = blockIdx.x >> 4;
  const int d = ((blockIdx.x & 15) << 8) + threadIdx.x;
  const int l0 = c * CL;
  {
    int t = threadIdx.x;
    if (t < CL * 8) {
      int r = t >> 3, j = (t & 7) * 4;
      *(float4*)&sBC[r][j] =
          *(const float4*)&ssm[(size_t)(l0 + r) * NPAD + R_TS + j];
    }
  }
  float Ac[N_ST];
#pragma unroll
  for (int n = 0; n < N_ST; ++n) Ac[n] = -__expf(A_log[d * N_ST + n]);
  const float bdt = b_dt[d], dpd = Dp[d];
  float s[N_ST];
  const float* ini = init + ((size_t)c * D_DIM + d) * N_ST;
#pragma unroll
  for (int n = 0; n < N_ST; ++n) s[n] = ini[n];
  __syncthreads();

  float dtn = dtraw[(size_t)l0 * D_DIM + d];
  float hn = b2f(hb[(size_t)l0 * D_DIM + d]);
  float gn = b2f(Pgate[(size_t)l0 * D_DIM + d]);
  for (int i = 0; i < CL; ++i) {
    const float x = dtn + bdt;
    const float hv = hn;
    const float gv = gn;
    const int ip = (i + 1 < CL) ? (i + 1) : i;
    dtn = dtraw[(size_t)(l0 + ip) * D_DIM + d];
    hn = b2f(hb[(size_t)(l0 + ip) * D_DIM + d]);
    gn = b2f(Pgate[(size_t)(l0 + ip) * D_DIM + d]);
    const float dt = (x > 20.f) ? x : __logf(1.f + __expf(x));
    const float dth = dt * hv;
    float y = 0.f;
#pragma unroll
    for (int n = 0; n < N_ST; ++n) {
      float dA = __expf(Ac[n] * dt);
      s[n] = fmaf(dA, s[n], dth * sBC[i][n]);
      y = fmaf(s[n], sBC[i][16 + n], y);
    }
    y = fmaf(hv, dpd, y);
    const float sg = gv / (1.f + __expf(-gv));
    yb[(size_t)(l0 + i) * D_DIM + d] = f2b(y * sg);
  }
}

// ---------------- launcher ----------------
extern "C" void kernel_launch(void* const* d_in, const int* in_sizes, int n_in,
                              void* d_out, int out_size, void* d_ws, size_t ws_size,
                              hipStream_t stream) {
  const float* X     = (const float*)d_in[0];
  const float* W_in  = (const float*)d_in[1];
  const float* ck    = (const float*)d_in[2];
  const float* cb    = (const float*)d_in[3];
  const float* W_x   = (const float*)d_in[4];
  const float* W_dt  = (const float*)d_in[5];
  const float* b_dt  = (const float*)d_in[6];
  const float* W_out = (const float*)d_in[7];
  const float* A_log = (const float*)d_in[8];
  const float* Dp    = (const float*)d_in[9];

  char* w = (char*)d_ws;
  size_t off = 0;
  auto alloc = [&](size_t bytes) {
    void* p = w + off;
    off = (off + bytes + 255) & ~(size_t)255;
    return p;
  };
  u16*   Xb    = (u16*)  alloc((size_t)L_DIM * H_DIM * 2);        //  0.0 -  8.4 MB
  u16*   WinT  = (u16*)  alloc((size_t)2 * D_DIM * H_DIM * 2);    //  8.4 - 42.0
  u16*   Phid  = (u16*)  alloc((size_t)L_DIM * D_DIM * 2);        // 42.0 - 58.8
  u16*   Pgate = (u16*)  alloc((size_t)L_DIM * D_DIM * 2);        // 58.8 - 75.6
  u16*   hb    = (u16*)  alloc((size_t)L_DIM * D_DIM * 2);        // 75.6 - 92.4
  u16*   WxT   = (u16*)  alloc((size_t)NPAD * D_DIM * 2);
  float* ssm   = (float*)alloc((size_t)L_DIM * NPAD * 4);
  u16*   tsb   = (u16*)  alloc((size_t)L_DIM * R_TS * 2);
  u16*   WdtT  = (u16*)  alloc((size_t)D_DIM * R_TS * 2);
  float* dtraw = (float*)alloc((size_t)L_DIM * D_DIM * 4);        // fp32 (r5 cfg)
  u16*   WoutT = (u16*)  alloc((size_t)H_DIM * D_DIM * 2);
  u16*   yb    = (u16*)  alloc((size_t)L_DIM * D_DIM * 2);        // ~166 MB linear
  // Aliases (disjoint lifetimes, round-5-proven layout):
  //  xpart (16.8 MB, steps 6-7)       @0      (Xb+WinT dead after step 3)
  //  sCb/aPb (2x16.8 MB, steps 10-11) @0/16.8 (same dead region)
  //  initb (16.8 MB, steps 11-12)     @Phid   (dead after step 4; exact fit)
  //  opartb bf16 (33.6 MB, steps 14-15) @0    (Xb+WinT region, dead by 14)
  float* xpart  = (float*)d_ws;
  float* sCb    = (float*)d_ws;
  float* aPb    = (float*)((char*)d_ws + (size_t)NC * D_DIM * N_ST * 4);
  float* initb  = (float*)Phid;
  u16*   opartb = (u16*)d_ws;
  (void)ws_size;

  // 1) X -> bf16
  k_f32_to_bf16<<<(L_DIM * H_DIM / 4 + 255) / 256, 256, 0, stream>>>(
      X, Xb, L_DIM * H_DIM / 4);
  // 2) W_in [H,2D] -> WinT [2D,H]
  k_transpose_bf16<<<dim3(2 * D_DIM / 32, H_DIM / 32), dim3(32, 8), 0, stream>>>(
      W_in, WinT, H_DIM, 2 * D_DIM);
  // 3) {Phid|Pgate} = X * W_in   (8-phase 256^2, bf16 outputs)
  k_gemm256<<<dim3(2 * D_DIM / 256, L_DIM / 256), 512, 0, stream>>>(
      Xb, WinT, Phid, Pgate, L_DIM, 2 * D_DIM, H_DIM, D_DIM);
  // 4) conv + silu -> hb (bf16), scalar form
  k_conv_silu<<<L_DIM * D_DIM / 256, 256, 0, stream>>>(Phid, ck, cb, hb);
  // 5) W_x [D,160] -> WxT [256,D] zero-padded
  k_transpose_bf16<<<dim3(NPAD / 32, D_DIM / 32), dim3(32, 8), 0, stream>>>(
      W_x, WxT, D_DIM, R_TS + 2 * N_ST);
  // 6-7) ssm partials = h * W_x  (split-K=8), reduce + ts extract
  k_gemm_bt_split<<<dim3(NPAD / 128, L_DIM / 128, KSP), 256, 0, stream>>>(
      hb, WxT, xpart, L_DIM, NPAD, D_DIM, D_DIM / KSP);
  k_xred<<<L_DIM * NPAD / 4 / 256, 256, 0, stream>>>(xpart, ssm, tsb);
  // 8) W_dt [128,D] -> WdtT [D,128]
  k_transpose_bf16<<<dim3(D_DIM / 32, R_TS / 32), dim3(32, 8), 0, stream>>>(
      W_dt, WdtT, R_TS, D_DIM);
  // 9) dtraw = ts * W_dt  [L, D]  (fp32 out, r5 config)
  k_gemm_bt<<<dim3(D_DIM / 128, L_DIM / 128), 256, 0, stream>>>(
      tsb, WdtT, dtraw, L_DIM, D_DIM, R_TS);
  // 10-12) chunked scan (NC=64 chunks of CL=32)
  k_scan_partial<<<NC * (D_DIM / 256), 256, 0, stream>>>(
      dtraw, b_dt, hb, ssm, A_log, sCb, aPb);
  k_scan_combine<<<D_DIM * N_ST / 256, 256, 0, stream>>>(sCb, aPb, initb);
  k_scan_final<<<NC * (D_DIM / 256), 256, 0, stream>>>(
      dtraw, b_dt, hb, ssm, A_log, initb, Pgate, Dp, yb);
  // 13) W_out [D,H] -> WoutT [H,D]
  k_transpose_bf16<<<dim3(H_DIM / 32, D_DIM / 32), dim3(32, 8), 0, stream>>>(
      W_out, WoutT, D_DIM, H_DIM);
  // 14-15) out = y * W_out  (8-phase 256^2, split-K=4, bf16 partials) + reduce
  k_gemm256s<<<dim3(H_DIM / 256, L_DIM / 256, KSPO), 512, 0, stream>>>(
      yb, WoutT, opartb, L_DIM, H_DIM, D_DIM, D_DIM / KSPO);
  k_ored<<<L_DIM * H_DIM / 4 / 256, 256, 0, stream>>>(opartb, (float*)d_out);
}

// Round 11
// 306.844 us; speedup vs baseline: 1.1438x; 1.0372x over previous
//
#include <hip/hip_runtime.h>

// Problem dims
#define L_DIM 2048
#define H_DIM 2048
#define D_DIM 4096
#define N_ST  16
#define R_TS  128
#define NPAD  256   // padded R+2N (160 -> 256)
#define NC    64    // scan chunks (64 proven best: 128 regressed, r8)
#define CL    32    // steps per chunk (NC*CL = L)
#define KSP   8     // split-K factor for x_proj
#define KSPO  4     // split-K factor for out_proj

typedef unsigned short u16;
typedef short bf16x8 __attribute__((ext_vector_type(8)));
typedef float f32x4 __attribute__((ext_vector_type(4)));

__device__ __forceinline__ u16 f2b(float x) {
  union { float f; unsigned u; } v; v.f = x;
  unsigned r = v.u + 0x7fffu + ((v.u >> 16) & 1u);
  return (u16)(r >> 16);
}
__device__ __forceinline__ float b2f(u16 v) {
  union { unsigned u; float f; } x; x.u = (unsigned)v << 16; return x.f;
}

__device__ __forceinline__ void gl2lds16(const u16* g, u16* l) {
  __builtin_amdgcn_global_load_lds(
      (const __attribute__((address_space(1))) unsigned*)g,
      (__attribute__((address_space(3))) unsigned*)l, 16, 0, 0);
}

// ======= fused preprocessing: X->bf16 + 4 weight transposes (1 launch) ======
// Block ranges: [0,4096) X convert; [4096,20480) W_in T; [20480,21504) W_x T;
// [21504,22016) W_dt T; [22016,30208) W_out T. Math identical to the old
// k_f32_to_bf16 / k_transpose_bf16 kernels (bit-identical outputs).
#define PREP_NB 30208
__global__ __launch_bounds__(256)
void k_prep(const float* __restrict__ X, u16* __restrict__ Xb,
            const float* __restrict__ W_in, u16* __restrict__ WinT,
            const float* __restrict__ W_x, u16* __restrict__ WxT,
            const float* __restrict__ W_dt, u16* __restrict__ WdtT,
            const float* __restrict__ W_out, u16* __restrict__ WoutT) {
  __shared__ float t[32][33];
  const int b = blockIdx.x;
  if (b < 4096) {                       // X: L*H/4 = 1M float4 groups
    int i = b * 256 + threadIdx.x;
    float4 v = ((const float4*)X)[i];
    ushort4 o;
    o.x = f2b(v.x); o.y = f2b(v.y); o.z = f2b(v.z); o.w = f2b(v.w);
    ((ushort4*)Xb)[i] = o;
    return;
  }
  const float* src; u16* dst; int R, C, CB, rel;
  if (b < 20480)      { rel = b - 4096;  src = W_in;  dst = WinT;
                        R = H_DIM; C = 2 * D_DIM; CB = (2 * D_DIM) / 32; }
  else if (b < 21504) { rel = b - 20480; src = W_x;   dst = WxT;
                        R = D_DIM; C = R_TS + 2 * N_ST; CB = NPAD / 32; }
  else if (b < 22016) { rel = b - 21504; src = W_dt;  dst = WdtT;
                        R = R_TS;  C = D_DIM; CB = D_DIM / 32; }
  else                { rel = b - 22016; src = W_out; dst = WoutT;
                        R = D_DIM; C = H_DIM; CB = H_DIM / 32; }
  const int x = threadIdx.x & 31, y = threadIdx.x >> 5;   // 32 x 8
  const int c0 = (rel % CB) * 32, r0 = (rel / CB) * 32;
#pragma unroll
  for (int i = 0; i < 4; ++i) {
    int r = r0 + y + i * 8, c = c0 + x;
    t[y + i * 8][x] = (c < C) ? src[(size_t)r * C + c] : 0.f;
  }
  __syncthreads();
#pragma unroll
  for (int i = 0; i < 4; ++i) {
    int cc = c0 + y + i * 8;
    dst[(size_t)cc * R + r0 + x] = f2b(t[x][y + i * 8]);
  }
}

// ============ 256x256 8-phase bf16 MFMA GEMM: C = A[M,K] * Bt[N,K]^T ========
// Output split into two bf16 [M, NS] buffers (cols < NS -> C0, else C1).
// No XCD swizzle: with gridDim.x=32 the linear mapping gives XCD = bn%8
// (B-panel per-XCD L2 locality); r7 swizzle tripled FETCH (143 MB) for 0 gain.
__global__ __launch_bounds__(512, 2)
void k_gemm256(const u16* __restrict__ A, const u16* __restrict__ Bt,
               u16* __restrict__ C0, u16* __restrict__ C1,
               int M, int N, int K, int NS) {
  __shared__ u16 lA[2][256][64];
  __shared__ u16 lB[2][256][64];
  const int tid = threadIdx.x;
  const int w = tid >> 6, lane = tid & 63;
  const int wm = w >> 2, wn = w & 3;          // 2 x 4 waves
  const int fr = lane & 15, fq = lane >> 4;
  const int xr = (fr & 7) << 4;               // read-side XOR (bytes)
  const int sr = lane >> 3;                   // stage row-in-group 0..7
  const int sc = ((lane & 7) ^ sr) << 3;      // stage source col (elems), pre-swizzled
  const int bn = blockIdx.x, bm = blockIdx.y;
  const u16* Ag = A + (size_t)bm * 256 * K;
  const u16* Bg = Bt + (size_t)bn * 256 * K;
  const int NT = K >> 6;

  f32x4 acc[8][4];
#pragma unroll
  for (int i = 0; i < 8; ++i)
#pragma unroll
    for (int j = 0; j < 4; ++j) acc[i][j] = (f32x4){0.f, 0.f, 0.f, 0.f};

  bf16x8 af[4][2];
  bf16x8 bfr[4][2];

#define STAGE_HALF(LT, G, TT, H) do {                                   \
    const int b_ = (TT) & 1; const int kt_ = (TT) << 6;                 \
    const u16* g0_ = (G) + (size_t)((H) * 128 + w * 8 + sr) * K + kt_ + sc; \
    u16* l0_ = &LT[b_][(H) * 128 + w * 8][0];                           \
    gl2lds16(g0_, l0_);                                                 \
    gl2lds16(g0_ + (size_t)64 * K, l0_ + 64 * 64);                      \
  } while (0)

#define LDA_HALF(BB, MH) do {                                           \
    const char* bA_ = (const char*)lA + (size_t)(BB) * 32768;           \
    _Pragma("unroll")                                                   \
    for (int m_ = 0; m_ < 4; ++m_) {                                    \
      const char* rp_ = bA_ + (wm * 128 + (MH) * 64 + m_ * 16 + fr) * 128; \
      af[m_][0] = *(const bf16x8*)(rp_ + ((fq << 4) ^ xr));             \
      af[m_][1] = *(const bf16x8*)(rp_ + ((64 | (fq << 4)) ^ xr));      \
    } } while (0)

#define LDB_HALF(BB, NH) do {                                           \
    const char* bB_ = (const char*)lB + (size_t)(BB) * 32768;           \
    _Pragma("unroll")                                                   \
    for (int n_ = 0; n_ < 2; ++n_) {                                    \
      const char* rp_ = bB_ + (wn * 64 + ((NH) * 2 + n_) * 16 + fr) * 128; \
      bfr[(NH) * 2 + n_][0] = *(const bf16x8*)(rp_ + ((fq << 4) ^ xr)); \
      bfr[(NH) * 2 + n_][1] = *(const bf16x8*)(rp_ + ((64 | (fq << 4)) ^ xr)); \
    } } while (0)

#define MFMA_Q(MH, NH) do {                                             \
    __builtin_amdgcn_s_setprio(1);                                      \
    _Pragma("unroll")                                                   \
    for (int m_ = 0; m_ < 4; ++m_)                                      \
      _Pragma("unroll")                                                 \
      for (int n_ = 0; n_ < 2; ++n_) {                                  \
        acc[(MH)*4+m_][(NH)*2+n_] = __builtin_amdgcn_mfma_f32_16x16x32_bf16( \
            af[m_][0], bfr[(NH)*2+n_][0], acc[(MH)*4+m_][(NH)*2+n_], 0, 0, 0); \
        acc[(MH)*4+m_][(NH)*2+n_] = __builtin_amdgcn_mfma_f32_16x16x32_bf16( \
            af[m_][1], bfr[(NH)*2+n_][1], acc[(MH)*4+m_][(NH)*2+n_], 0, 0, 0); \
      }                                                                 \
    __builtin_amdgcn_s_setprio(0);                                      \
  } while (0)

#define BAR() __builtin_amdgcn_s_barrier()
#define LGKM0() do { asm volatile("s_waitcnt lgkmcnt(0)" ::: "memory"); \
                     __builtin_amdgcn_sched_barrier(0); } while (0)

  STAGE_HALF(lA, Ag, 0, 0); STAGE_HALF(lA, Ag, 0, 1);
  STAGE_HALF(lB, Bg, 0, 0); STAGE_HALF(lB, Bg, 0, 1);
  STAGE_HALF(lB, Bg, 1, 0); STAGE_HALF(lB, Bg, 1, 1);
  asm volatile("s_waitcnt vmcnt(4)" ::: "memory");
  BAR();

  for (int t = 0; t < NT; ++t) {
    const int b = t & 1;
    const int ta = (t + 1 == NT) ? 0 : t + 1;
    const int tb = (t + 2 >= NT) ? (t + 2 - NT) : t + 2;
    LDA_HALF(b, 0); LDB_HALF(b, 0);
    STAGE_HALF(lA, Ag, ta, 0);
    BAR(); LGKM0();
    MFMA_Q(0, 0);
    BAR();
    LDB_HALF(b, 1);
    STAGE_HALF(lA, Ag, ta, 1);
    BAR(); LGKM0();
    MFMA_Q(0, 1);
    BAR();
    LDA_HALF(b, 1);
    STAGE_HALF(lB, Bg, tb, 0);
    BAR(); LGKM0();
    MFMA_Q(1, 0);
    BAR();
    STAGE_HALF(lB, Bg, tb, 1);
    BAR(); LGKM0();
    MFMA_Q(1, 1);
    asm volatile("s_waitcnt vmcnt(4)" ::: "memory");
    BAR();
  }
  asm volatile("s_waitcnt vmcnt(0)" ::: "memory");

#pragma unroll
  for (int mi = 0; mi < 8; ++mi)
#pragma unroll
    for (int n = 0; n < 4; ++n) {
      int col = bn * 256 + wn * 64 + n * 16 + fr;
      u16* Cd = C0;
      if (col >= NS) { Cd = C1; col -= NS; }
      const int row0 = bm * 256 + wm * 128 + mi * 16 + fq * 4;
#pragma unroll
      for (int j = 0; j < 4; ++j)
        Cd[(size_t)(row0 + j) * NS + col] = f2b(acc[mi][n][j]);
    }
}

// ===== split-K 8-phase 256^2 kernel: bf16 partials per z =====
// (r5/r6 measured: partial stores + separate reduce >> atomicAdd epilogue)
__global__ __launch_bounds__(512, 2)
void k_gemm256s(const u16* __restrict__ A, const u16* __restrict__ Bt,
                u16* __restrict__ Cp, int M, int N, int K, int klen) {
  __shared__ u16 lA[2][256][64];
  __shared__ u16 lB[2][256][64];
  const int tid = threadIdx.x;
  const int w = tid >> 6, lane = tid & 63;
  const int wm = w >> 2, wn = w & 3;
  const int fr = lane & 15, fq = lane >> 4;
  const int xr = (fr & 7) << 4;
  const int sr = lane >> 3;
  const int sc = ((lane & 7) ^ sr) << 3;
  const int bn = blockIdx.x, bm = blockIdx.y, z = blockIdx.z;
  const int k0 = z * klen;
  const u16* Ag = A + (size_t)bm * 256 * K;
  const u16* Bg = Bt + (size_t)bn * 256 * K;
  const int NT = klen >> 6;
  u16* C = Cp + (size_t)z * M * N;

  f32x4 acc[8][4];
#pragma unroll
  for (int i = 0; i < 8; ++i)
#pragma unroll
    for (int j = 0; j < 4; ++j) acc[i][j] = (f32x4){0.f, 0.f, 0.f, 0.f};

  bf16x8 af[4][2];
  bf16x8 bfr[4][2];

#undef STAGE_HALF
#define STAGE_HALF(LT, G, TT, H) do {                                   \
    const int b_ = (TT) & 1; const int kt_ = ((TT) << 6) + k0;          \
    const u16* g0_ = (G) + (size_t)((H) * 128 + w * 8 + sr) * K + kt_ + sc; \
    u16* l0_ = &LT[b_][(H) * 128 + w * 8][0];                           \
    gl2lds16(g0_, l0_);                                                 \
    gl2lds16(g0_ + (size_t)64 * K, l0_ + 64 * 64);                      \
  } while (0)

  STAGE_HALF(lA, Ag, 0, 0); STAGE_HALF(lA, Ag, 0, 1);
  STAGE_HALF(lB, Bg, 0, 0); STAGE_HALF(lB, Bg, 0, 1);
  STAGE_HALF(lB, Bg, 1, 0); STAGE_HALF(lB, Bg, 1, 1);
  asm volatile("s_waitcnt vmcnt(4)" ::: "memory");
  BAR();

  for (int t = 0; t < NT; ++t) {
    const int b = t & 1;
    const int ta = (t + 1 == NT) ? 0 : t + 1;
    const int tb = (t + 2 >= NT) ? (t + 2 - NT) : t + 2;
    LDA_HALF(b, 0); LDB_HALF(b, 0);
    STAGE_HALF(lA, Ag, ta, 0);
    BAR(); LGKM0();
    MFMA_Q(0, 0);
    BAR();
    LDB_HALF(b, 1);
    STAGE_HALF(lA, Ag, ta, 1);
    BAR(); LGKM0();
    MFMA_Q(0, 1);
    BAR();
    LDA_HALF(b, 1);
    STAGE_HALF(lB, Bg, tb, 0);
    BAR(); LGKM0();
    MFMA_Q(1, 0);
    BAR();
    STAGE_HALF(lB, Bg, tb, 1);
    BAR(); LGKM0();
    MFMA_Q(1, 1);
    asm volatile("s_waitcnt vmcnt(4)" ::: "memory");
    BAR();
  }
  asm volatile("s_waitcnt vmcnt(0)" ::: "memory");

#undef STAGE_HALF
#undef LDA_HALF
#undef LDB_HALF
#undef MFMA_Q
#undef BAR
#undef LGKM0

#pragma unroll
  for (int mi = 0; mi < 8; ++mi)
#pragma unroll
    for (int n = 0; n < 4; ++n) {
      const int col = bn * 256 + wn * 64 + n * 16 + fr;
      const int row0 = bm * 256 + wm * 128 + mi * 16 + fq * 4;
#pragma unroll
      for (int j = 0; j < 4; ++j)
        C[(size_t)(row0 + j) * N + col] = f2b(acc[mi][n][j]);
    }
}

// -------- reduce out_proj bf16 split-K partials -> fp32 output --------------
__global__ __launch_bounds__(256)
void k_ored(const u16* __restrict__ Cp, float* __restrict__ out) {
  const int i = blockIdx.x * 256 + threadIdx.x;   // over M*N/4
  f32x4 s = (f32x4){0.f, 0.f, 0.f, 0.f};
#pragma unroll
  for (int z = 0; z < KSPO; ++z) {
    ushort4 p = *(const ushort4*)&Cp[(size_t)z * L_DIM * H_DIM + (size_t)i * 4];
    s[0] += b2f(p.x); s[1] += b2f(p.y); s[2] += b2f(p.z); s[3] += b2f(p.w);
  }
  *(f32x4*)&out[(size_t)i * 4] = s;
}

// ---------------- bf16 MFMA GEMM (128x128, m97-style): C = A * Bt^T ---------
// fp32-output variant (dt_proj; fp32 dtraw proven best r10)
__global__ __launch_bounds__(256)
void k_gemm_bt(const u16* __restrict__ A, const u16* __restrict__ Bt,
               float* __restrict__ C, int M, int N, int K) {
  __shared__ u16 sA[128 * 64];
  __shared__ u16 sB[128 * 64];
  const int tid = threadIdx.x;
  const int wave = tid >> 6, lane = tid & 63;
  const int bn = blockIdx.x, bm = blockIdx.y;
  const int wm = wave >> 1, wn = wave & 1;
  const int fr = lane & 15, fq = lane >> 4;
  const int srow = lane >> 3;
  const int scol = (lane & 7) * 8;

  const u16* Ab = A + (size_t)bm * 128 * K;
  const u16* Bb = Bt + (size_t)bn * 128 * K;

  f32x4 acc[4][4];
#pragma unroll
  for (int i = 0; i < 4; ++i)
#pragma unroll
    for (int j = 0; j < 4; ++j) acc[i][j] = (f32x4){0.f, 0.f, 0.f, 0.f};

  for (int kt = 0; kt < K; kt += 64) {
    __syncthreads();
#pragma unroll
    for (int i = 0; i < 4; ++i) {
      int ci = wave * 4 + i;
      int row = ci * 8 + srow;
      gl2lds16(Ab + (size_t)row * K + kt + scol, &sA[ci * 512]);
      gl2lds16(Bb + (size_t)row * K + kt + scol, &sB[ci * 512]);
    }
    __syncthreads();
#pragma unroll
    for (int kk = 0; kk < 2; ++kk) {
      bf16x8 af[4], bfr[4];
#pragma unroll
      for (int mf = 0; mf < 4; ++mf)
        af[mf] = *(const bf16x8*)&sA[(wm * 64 + mf * 16 + fr) * 64 + kk * 32 + fq * 8];
#pragma unroll
      for (int nf = 0; nf < 4; ++nf)
        bfr[nf] = *(const bf16x8*)&sB[(wn * 64 + nf * 16 + fr) * 64 + kk * 32 + fq * 8];
#pragma unroll
      for (int mf = 0; mf < 4; ++mf)
#pragma unroll
        for (int nf = 0; nf < 4; ++nf)
          acc[mf][nf] = __builtin_amdgcn_mfma_f32_16x16x32_bf16(
              af[mf], bfr[nf], acc[mf][nf], 0, 0, 0);
    }
  }

#pragma unroll
  for (int mf = 0; mf < 4; ++mf)
#pragma unroll
    for (int nf = 0; nf < 4; ++nf) {
      int col = bn * 128 + wn * 64 + nf * 16 + fr;
#pragma unroll
      for (int j = 0; j < 4; ++j) {
        int row = bm * 128 + wm * 64 + mf * 16 + fq * 4 + j;
        C[(size_t)row * N + col] = acc[mf][nf][j];
      }
    }
}

// ---------------- split-K variant (blockIdx.z = K-slice), partial outputs ----
__global__ __launch_bounds__(256)
void k_gemm_bt_split(const u16* __restrict__ A, const u16* __restrict__ Bt,
                     float* __restrict__ Cp, int M, int N, int K, int klen) {
  __shared__ u16 sA[128 * 64];
  __shared__ u16 sB[128 * 64];
  const int tid = threadIdx.x;
  const int wave = tid >> 6, lane = tid & 63;
  const int bn = blockIdx.x, bm = blockIdx.y, z = blockIdx.z;
  const int wm = wave >> 1, wn = wave & 1;
  const int fr = lane & 15, fq = lane >> 4;
  const int srow = lane >> 3;
  const int scol = (lane & 7) * 8;
  const int k0 = z * klen;
  float* C = Cp + (size_t)z * M * N;

  const u16* Ab = A + (size_t)bm * 128 * K;
  const u16* Bb = Bt + (size_t)bn * 128 * K;

  f32x4 acc[4][4];
#pragma unroll
  for (int i = 0; i < 4; ++i)
#pragma unroll
    for (int j = 0; j < 4; ++j) acc[i][j] = (f32x4){0.f, 0.f, 0.f, 0.f};

  for (int kt = k0; kt < k0 + klen; kt += 64) {
    __syncthreads();
#pragma unroll
    for (int i = 0; i < 4; ++i) {
      int ci = wave * 4 + i;
      int row = ci * 8 + srow;
      gl2lds16(Ab + (size_t)row * K + kt + scol, &sA[ci * 512]);
      gl2lds16(Bb + (size_t)row * K + kt + scol, &sB[ci * 512]);
    }
    __syncthreads();
#pragma unroll
    for (int kk = 0; kk < 2; ++kk) {
      bf16x8 af[4], bfr[4];
#pragma unroll
      for (int mf = 0; mf < 4; ++mf)
        af[mf] = *(const bf16x8*)&sA[(wm * 64 + mf * 16 + fr) * 64 + kk * 32 + fq * 8];
#pragma unroll
      for (int nf = 0; nf < 4; ++nf)
        bfr[nf] = *(const bf16x8*)&sB[(wn * 64 + nf * 16 + fr) * 64 + kk * 32 + fq * 8];
#pragma unroll
      for (int mf = 0; mf < 4; ++mf)
#pragma unroll
        for (int nf = 0; nf < 4; ++nf)
          acc[mf][nf] = __builtin_amdgcn_mfma_f32_16x16x32_bf16(
              af[mf], bfr[nf], acc[mf][nf], 0, 0, 0);
    }
  }

#pragma unroll
  for (int mf = 0; mf < 4; ++mf)
#pragma unroll
    for (int nf = 0; nf < 4; ++nf) {
      int col = bn * 128 + wn * 64 + nf * 16 + fr;
#pragma unroll
      for (int j = 0; j < 4; ++j) {
        int row = bm * 128 + wm * 64 + mf * 16 + fq * 4 + j;
        C[(size_t)row * N + col] = acc[mf][nf][j];
      }
    }
}

// -------- reduce split-K partials -> ssm fp32; fuse time_step bf16 extract ---
__global__ __launch_bounds__(256)
void k_xred(const float* __restrict__ Cp, float* __restrict__ ssm,
            u16* __restrict__ tsb) {
  int i = blockIdx.x * 256 + threadIdx.x;   // over L*NPAD/4
  int l = i >> 6, g = i & 63;
  f32x4 s = (f32x4){0.f, 0.f, 0.f, 0.f};
#pragma unroll
  for (int z = 0; z < KSP; ++z)
    s += *(const f32x4*)&Cp[(size_t)z * L_DIM * NPAD + (size_t)l * NPAD + g * 4];
  *(f32x4*)&ssm[(size_t)l * NPAD + g * 4] = s;
  if (g < 32) {
    ushort4 o;
    o.x = f2b(s[0]); o.y = f2b(s[1]); o.z = f2b(s[2]); o.w = f2b(s[3]);
    *(ushort4*)&tsb[(size_t)l * R_TS + g * 4] = o;
  }
}

// ---------------- depthwise causal conv (K=4) + bias + silu -> bf16 ---------
// scalar r5-proven form
__global__ __launch_bounds__(256)
void k_conv_silu(const u16* __restrict__ Phid, const float* __restrict__ ck,
                 const float* __restrict__ cb, u16* __restrict__ hb) {
  int idx = blockIdx.x * 256 + threadIdx.x;       // l*D + d
  int l = idx >> 12, d = idx & (D_DIM - 1);
  float acc = cb[d];
#pragma unroll
  for (int k = 0; k < 4; ++k) {
    int ll = l - 3 + k;
    if (ll >= 0) acc = fmaf(b2f(Phid[(size_t)ll * D_DIM + d]), ck[d * 4 + k], acc);
  }
  float sv = acc / (1.f + __expf(-acc));
  hb[idx] = f2b(sv);
}

// ---------------- chunked selective scan (NC=64, CL=32) ----------------
__global__ __launch_bounds__(256)
void k_scan_partial(const float* __restrict__ dtraw, const float* __restrict__ b_dt,
                    const u16* __restrict__ hb, const float* __restrict__ ssm,
                    const float* __restrict__ A_log, float* __restrict__ sC,
                    float* __restrict__ aP) {
  __shared__ float sBl[CL][16];
  const int c = blockIdx.x >> 4;
  const int d = ((blockIdx.x & 15) << 8) + threadIdx.x;
  const int l0 = c * CL;
  {
    int t = threadIdx.x;
    if (t < CL * 4) {
      int r = t >> 2, j = (t & 3) * 4;
      *(float4*)&sBl[r][j] =
          *(const float4*)&ssm[(size_t)(l0 + r) * NPAD + R_TS + j];
    }
  }
  float Ac[N_ST];
#pragma unroll
  for (int n = 0; n < N_ST; ++n) Ac[n] = -__expf(A_log[d * N_ST + n]);
  const float bdt = b_dt[d];
  float s[N_ST], ap[N_ST];
#pragma unroll
  for (int n = 0; n < N_ST; ++n) { s[n] = 0.f; ap[n] = 1.f; }
  __syncthreads();

  float dtn = dtraw[(size_t)l0 * D_DIM + d];
  float hn = b2f(hb[(size_t)l0 * D_DIM + d]);
  for (int i = 0; i < CL; ++i) {
    const float x = dtn + bdt;
    const float hv = hn;
    const int ip = (i + 1 < CL) ? (i + 1) : i;
    dtn = dtraw[(size_t)(l0 + ip) * D_DIM + d];
    hn = b2f(hb[(size_t)(l0 + ip) * D_DIM + d]);
    const float dt = (x > 20.f) ? x : __logf(1.f + __expf(x));
    const float dth = dt * hv;
#pragma unroll
    for (int n = 0; n < N_ST; ++n) {
      float dA = __expf(Ac[n] * dt);
      s[n] = fmaf(dA, s[n], dth * sBl[i][n]);
      ap[n] *= dA;
    }
  }
  float* so = sC + ((size_t)c * D_DIM + d) * N_ST;
  float* ao = aP + ((size_t)c * D_DIM + d) * N_ST;
#pragma unroll
  for (int n = 0; n < N_ST; ++n) { so[n] = s[n]; ao[n] = ap[n]; }
}

__global__ __launch_bounds__(256)
void k_scan_combine(const float* __restrict__ sC, const float* __restrict__ aP,
                    float* __restrict__ init) {
  const int i = blockIdx.x * 256 + threadIdx.x;
  float s = 0.f;
  for (int c = 0; c < NC; ++c) {
    init[(size_t)c * (D_DIM * N_ST) + i] = s;
    s = fmaf(aP[(size_t)c * (D_DIM * N_ST) + i], s,
             sC[(size_t)c * (D_DIM * N_ST) + i]);
  }
}

__global__ __launch_bounds__(256)
void k_scan_final(const float* __restrict__ dtraw, const float* __restrict__ b_dt,
                  const u16* __restrict__ hb, const float* __restrict__ ssm,
                  const float* __restrict__ A_log, const float* __restrict__ init,
                  const u16* __restrict__ Pgate, const float* __restrict__ Dp,
                  u16* __restrict__ yb) {
  __shared__ float sBC[CL][32];
  const int c = blockIdx.x >> 4;
  const int d = ((blockIdx.x & 15) << 8) + threadIdx.x;
  const int l0 = c * CL;
  {
    int t = threadIdx.x;
    if (t < CL * 8) {
      int r = t >> 3, j = (t & 7) * 4;
      *(float4*)&sBC[r][j] =
          *(const float4*)&ssm[(size_t)(l0 + r) * NPAD + R_TS + j];
    }
  }
  float Ac[N_ST];
#pragma unroll
  for (int n = 0; n < N_ST; ++n) Ac[n] = -__expf(A_log[d * N_ST + n]);
  const float bdt = b_dt[d], dpd = Dp[d];
  float s[N_ST];
  const float* ini = init + ((size_t)c * D_DIM + d) * N_ST;
#pragma unroll
  for (int n = 0; n < N_ST; ++n) s[n] = ini[n];
  __syncthreads();

  float dtn = dtraw[(size_t)l0 * D_DIM + d];
  float hn = b2f(hb[(size_t)l0 * D_DIM + d]);
  float gn = b2f(Pgate[(size_t)l0 * D_DIM + d]);
  for (int i = 0; i < CL; ++i) {
    const float x = dtn + bdt;
    const float hv = hn;
    const float gv = gn;
    const int ip = (i + 1 < CL) ? (i + 1) : i;
    dtn = dtraw[(size_t)(l0 + ip) * D_DIM + d];
    hn = b2f(hb[(size_t)(l0 + ip) * D_DIM + d]);
    gn = b2f(Pgate[(size_t)(l0 + ip) * D_DIM + d]);
    const float dt = (x > 20.f) ? x : __logf(1.f + __expf(x));
    const float dth = dt * hv;
    float y = 0.f;
#pragma unroll
    for (int n = 0; n < N_ST; ++n) {
      float dA = __expf(Ac[n] * dt);
      s[n] = fmaf(dA, s[n], dth * sBC[i][n]);
      y = fmaf(s[n], sBC[i][16 + n], y);
    }
    y = fmaf(hv, dpd, y);
    const float sg = gv / (1.f + __expf(-gv));
    yb[(size_t)(l0 + i) * D_DIM + d] = f2b(y * sg);
  }
}

// ---------------- launcher ----------------
extern "C" void kernel_launch(void* const* d_in, const int* in_sizes, int n_in,
                              void* d_out, int out_size, void* d_ws, size_t ws_size,
                              hipStream_t stream) {
  const float* X     = (const float*)d_in[0];
  const float* W_in  = (const float*)d_in[1];
  const float* ck    = (const float*)d_in[2];
  const float* cb    = (const float*)d_in[3];
  const float* W_x   = (const float*)d_in[4];
  const float* W_dt  = (const float*)d_in[5];
  const float* b_dt  = (const float*)d_in[6];
  const float* W_out = (const float*)d_in[7];
  const float* A_log = (const float*)d_in[8];
  const float* Dp    = (const float*)d_in[9];

  char* w = (char*)d_ws;
  size_t off = 0;
  auto alloc = [&](size_t bytes) {
    void* p = w + off;
    off = (off + bytes + 255) & ~(size_t)255;
    return p;
  };
  u16*   Xb    = (u16*)  alloc((size_t)L_DIM * H_DIM * 2);        //  0.0 -  8.4 MB
  u16*   WinT  = (u16*)  alloc((size_t)2 * D_DIM * H_DIM * 2);    //  8.4 - 42.0
  u16*   Phid  = (u16*)  alloc((size_t)L_DIM * D_DIM * 2);        // 42.0 - 58.8
  u16*   Pgate = (u16*)  alloc((size_t)L_DIM * D_DIM * 2);        // 58.8 - 75.6
  u16*   hb    = (u16*)  alloc((size_t)L_DIM * D_DIM * 2);        // 75.6 - 92.4
  u16*   WxT   = (u16*)  alloc((size_t)NPAD * D_DIM * 2);
  float* ssm   = (float*)alloc((size_t)L_DIM * NPAD * 4);
  u16*   tsb   = (u16*)  alloc((size_t)L_DIM * R_TS * 2);
  u16*   WdtT  = (u16*)  alloc((size_t)D_DIM * R_TS * 2);
  float* dtraw = (float*)alloc((size_t)L_DIM * D_DIM * 4);        // fp32 (r10 cfg)
  u16*   WoutT = (u16*)  alloc((size_t)H_DIM * D_DIM * 2);
  u16*   yb    = (u16*)  alloc((size_t)L_DIM * D_DIM * 2);        // ~166 MB linear
  // Aliases (disjoint lifetimes, round-5-proven layout):
  //  xpart (16.8 MB, steps 6-7)       @0      (Xb+WinT dead after step 3)
  //  sCb/aPb (2x16.8 MB, steps 10-11) @0/16.8 (same dead region)
  //  initb (16.8 MB, steps 11-12)     @Phid   (dead after step 4; exact fit)
  //  opartb bf16 (33.6 MB, steps 14-15) @0    (Xb+WinT region, dead by 14)
  float* xpart  = (float*)d_ws;
  float* sCb    = (float*)d_ws;
  float* aPb    = (float*)((char*)d_ws + (size_t)NC * D_DIM * N_ST * 4);
  float* initb  = (float*)Phid;
  u16*   opartb = (u16*)d_ws;
  (void)ws_size;

  // 1) fused preprocessing: X->bf16 + W_in/W_x/W_dt/W_out transposes
  k_prep<<<PREP_NB, 256, 0, stream>>>(
      X, Xb, W_in, WinT, W_x, WxT, W_dt, WdtT, W_out, WoutT);
  // 3) {Phid|Pgate} = X * W_in   (8-phase 256^2, bf16 outputs)
  k_gemm256<<<dim3(2 * D_DIM / 256, L_DIM / 256), 512, 0, stream>>>(
      Xb, WinT, Phid, Pgate, L_DIM, 2 * D_DIM, H_DIM, D_DIM);
  // 4) conv + silu -> hb (bf16), scalar form
  k_conv_silu<<<L_DIM * D_DIM / 256, 256, 0, stream>>>(Phid, ck, cb, hb);
  // 6-7) ssm partials = h * W_x  (split-K=8), reduce + ts extract
  k_gemm_bt_split<<<dim3(NPAD / 128, L_DIM / 128, KSP), 256, 0, stream>>>(
      hb, WxT, xpart, L_DIM, NPAD, D_DIM, D_DIM / KSP);
  k_xred<<<L_DIM * NPAD / 4 / 256, 256, 0, stream>>>(xpart, ssm, tsb);
  // 9) dtraw = ts * W_dt  [L, D]  (fp32 out)
  k_gemm_bt<<<dim3(D_DIM / 128, L_DIM / 128), 256, 0, stream>>>(
      tsb, WdtT, dtraw, L_DIM, D_DIM, R_TS);
  // 10-12) chunked scan (NC=64 chunks of CL=32)
  k_scan_partial<<<NC * (D_DIM / 256), 256, 0, stream>>>(
      dtraw, b_dt, hb, ssm, A_log, sCb, aPb);
  k_scan_combine<<<D_DIM * N_ST / 256, 256, 0, stream>>>(sCb, aPb, initb);
  k_scan_final<<<NC * (D_DIM / 256), 256, 0, stream>>>(
      dtraw, b_dt, hb, ssm, A_log, initb, Pgate, Dp, yb);
  // 14-15) out = y * W_out  (8-phase 256^2, split-K=4, bf16 partials) + reduce
  k_gemm256s<<<dim3(H_DIM / 256, L_DIM / 256, KSPO), 512, 0, stream>>>(
      yb, WoutT, opartb, L_DIM, H_DIM, D_DIM, D_DIM / KSPO);
  k_ored<<<L_DIM * H_DIM / 4 / 256, 256, 0, stream>>>(opartb, (float*)d_out);
}

// Round 12
// 306.550 us; speedup vs baseline: 1.1449x; 1.0010x over previous
//
#include <hip/hip_runtime.h>

// Problem dims
#define L_DIM 2048
#define H_DIM 2048
#define D_DIM 4096
#define N_ST  16
#define R_TS  128
#define NPAD  256   // padded R+2N (160 -> 256)
#define NC    64    // scan chunks (64 proven best: 128 regressed, r8)
#define CL    32    // steps per chunk (NC*CL = L)
#define KSP   8     // split-K factor for x_proj
#define KSPO  4     // split-K factor for out_proj

typedef unsigned short u16;
typedef short bf16x8 __attribute__((ext_vector_type(8)));
typedef float f32x4 __attribute__((ext_vector_type(4)));

__device__ __forceinline__ u16 f2b(float x) {
  union { float f; unsigned u; } v; v.f = x;
  unsigned r = v.u + 0x7fffu + ((v.u >> 16) & 1u);
  return (u16)(r >> 16);
}
__device__ __forceinline__ float b2f(u16 v) {
  union { unsigned u; float f; } x; x.u = (unsigned)v << 16; return x.f;
}

__device__ __forceinline__ void gl2lds16(const u16* g, u16* l) {
  __builtin_amdgcn_global_load_lds(
      (const __attribute__((address_space(1))) unsigned*)g,
      (__attribute__((address_space(3))) unsigned*)l, 16, 0, 0);
}

// ======= fused preprocessing: X->bf16 + 4 weight transposes (1 launch) ======
#define PREP_NB 30208
__global__ __launch_bounds__(256)
void k_prep(const float* __restrict__ X, u16* __restrict__ Xb,
            const float* __restrict__ W_in, u16* __restrict__ WinT,
            const float* __restrict__ W_x, u16* __restrict__ WxT,
            const float* __restrict__ W_dt, u16* __restrict__ WdtT,
            const float* __restrict__ W_out, u16* __restrict__ WoutT) {
  __shared__ float t[32][33];
  const int b = blockIdx.x;
  if (b < 4096) {                       // X: L*H/4 = 1M float4 groups
    int i = b * 256 + threadIdx.x;
    float4 v = ((const float4*)X)[i];
    ushort4 o;
    o.x = f2b(v.x); o.y = f2b(v.y); o.z = f2b(v.z); o.w = f2b(v.w);
    ((ushort4*)Xb)[i] = o;
    return;
  }
  const float* src; u16* dst; int R, C, CB, rel;
  if (b < 20480)      { rel = b - 4096;  src = W_in;  dst = WinT;
                        R = H_DIM; C = 2 * D_DIM; CB = (2 * D_DIM) / 32; }
  else if (b < 21504) { rel = b - 20480; src = W_x;   dst = WxT;
                        R = D_DIM; C = R_TS + 2 * N_ST; CB = NPAD / 32; }
  else if (b < 22016) { rel = b - 21504; src = W_dt;  dst = WdtT;
                        R = R_TS;  C = D_DIM; CB = D_DIM / 32; }
  else                { rel = b - 22016; src = W_out; dst = WoutT;
                        R = D_DIM; C = H_DIM; CB = H_DIM / 32; }
  const int x = threadIdx.x & 31, y = threadIdx.x >> 5;   // 32 x 8
  const int c0 = (rel % CB) * 32, r0 = (rel / CB) * 32;
#pragma unroll
  for (int i = 0; i < 4; ++i) {
    int r = r0 + y + i * 8, c = c0 + x;
    t[y + i * 8][x] = (c < C) ? src[(size_t)r * C + c] : 0.f;
  }
  __syncthreads();
#pragma unroll
  for (int i = 0; i < 4; ++i) {
    int cc = c0 + y + i * 8;
    dst[(size_t)cc * R + r0 + x] = f2b(t[x][y + i * 8]);
  }
}

// ============ 256x256 8-phase bf16 MFMA GEMM: C = A[M,K] * Bt[N,K]^T ========
// r12: ONE barrier per phase [reads | stage | MFMA | sched_bar+s_barrier].
// Compiler-visible ds_reads -> counted lgkmcnt interleave (no full drain);
// sched_barrier(0) pins MFMAs (and their lgkm waits) before the barrier
// (rule #18 guard). Stage targets are >=1 barrier from their last readers.
__global__ __launch_bounds__(512, 2)
void k_gemm256(const u16* __restrict__ A, const u16* __restrict__ Bt,
               u16* __restrict__ C0, u16* __restrict__ C1,
               int M, int N, int K, int NS) {
  __shared__ u16 lA[2][256][64];
  __shared__ u16 lB[2][256][64];
  const int tid = threadIdx.x;
  const int w = tid >> 6, lane = tid & 63;
  const int wm = w >> 2, wn = w & 3;          // 2 x 4 waves
  const int fr = lane & 15, fq = lane >> 4;
  const int xr = (fr & 7) << 4;               // read-side XOR (bytes)
  const int sr = lane >> 3;                   // stage row-in-group 0..7
  const int sc = ((lane & 7) ^ sr) << 3;      // stage source col (elems), pre-swizzled
  const int bn = blockIdx.x, bm = blockIdx.y;
  const u16* Ag = A + (size_t)bm * 256 * K;
  const u16* Bg = Bt + (size_t)bn * 256 * K;
  const int NT = K >> 6;

  f32x4 acc[8][4];
#pragma unroll
  for (int i = 0; i < 8; ++i)
#pragma unroll
    for (int j = 0; j < 4; ++j) acc[i][j] = (f32x4){0.f, 0.f, 0.f, 0.f};

  bf16x8 af[4][2];
  bf16x8 bfr[4][2];

#define STAGE_HALF(LT, G, TT, H) do {                                   \
    const int b_ = (TT) & 1; const int kt_ = (TT) << 6;                 \
    const u16* g0_ = (G) + (size_t)((H) * 128 + w * 8 + sr) * K + kt_ + sc; \
    u16* l0_ = &LT[b_][(H) * 128 + w * 8][0];                           \
    gl2lds16(g0_, l0_);                                                 \
    gl2lds16(g0_ + (size_t)64 * K, l0_ + 64 * 64);                      \
  } while (0)

#define LDA_HALF(BB, MH) do {                                           \
    const char* bA_ = (const char*)lA + (size_t)(BB) * 32768;           \
    _Pragma("unroll")                                                   \
    for (int m_ = 0; m_ < 4; ++m_) {                                    \
      const char* rp_ = bA_ + (wm * 128 + (MH) * 64 + m_ * 16 + fr) * 128; \
      af[m_][0] = *(const bf16x8*)(rp_ + ((fq << 4) ^ xr));             \
      af[m_][1] = *(const bf16x8*)(rp_ + ((64 | (fq << 4)) ^ xr));      \
    } } while (0)

#define LDB_HALF(BB, NH) do {                                           \
    const char* bB_ = (const char*)lB + (size_t)(BB) * 32768;           \
    _Pragma("unroll")                                                   \
    for (int n_ = 0; n_ < 2; ++n_) {                                    \
      const char* rp_ = bB_ + (wn * 64 + ((NH) * 2 + n_) * 16 + fr) * 128; \
      bfr[(NH) * 2 + n_][0] = *(const bf16x8*)(rp_ + ((fq << 4) ^ xr)); \
      bfr[(NH) * 2 + n_][1] = *(const bf16x8*)(rp_ + ((64 | (fq << 4)) ^ xr)); \
    } } while (0)

#define MFMA_Q(MH, NH) do {                                             \
    __builtin_amdgcn_s_setprio(1);                                      \
    _Pragma("unroll")                                                   \
    for (int m_ = 0; m_ < 4; ++m_)                                      \
      _Pragma("unroll")                                                 \
      for (int n_ = 0; n_ < 2; ++n_) {                                  \
        acc[(MH)*4+m_][(NH)*2+n_] = __builtin_amdgcn_mfma_f32_16x16x32_bf16( \
            af[m_][0], bfr[(NH)*2+n_][0], acc[(MH)*4+m_][(NH)*2+n_], 0, 0, 0); \
        acc[(MH)*4+m_][(NH)*2+n_] = __builtin_amdgcn_mfma_f32_16x16x32_bf16( \
            af[m_][1], bfr[(NH)*2+n_][1], acc[(MH)*4+m_][(NH)*2+n_], 0, 0, 0); \
      }                                                                 \
    __builtin_amdgcn_s_setprio(0);                                      \
  } while (0)

// one barrier per phase: compiler fence + sched pin + hw barrier
#define BARF() do { asm volatile("" ::: "memory");                      \
                    __builtin_amdgcn_sched_barrier(0);                  \
                    __builtin_amdgcn_s_barrier();                       \
                    asm volatile("" ::: "memory"); } while (0)

  STAGE_HALF(lA, Ag, 0, 0); STAGE_HALF(lA, Ag, 0, 1);
  STAGE_HALF(lB, Bg, 0, 0); STAGE_HALF(lB, Bg, 0, 1);
  STAGE_HALF(lB, Bg, 1, 0); STAGE_HALF(lB, Bg, 1, 1);
  asm volatile("s_waitcnt vmcnt(4)" ::: "memory");
  BARF();

  for (int t = 0; t < NT; ++t) {
    const int b = t & 1;
    const int ta = (t + 1 == NT) ? 0 : t + 1;
    const int tb = (t + 2 >= NT) ? (t + 2 - NT) : t + 2;
    // phase 0
    LDA_HALF(b, 0); LDB_HALF(b, 0);
    STAGE_HALF(lA, Ag, ta, 0);
    MFMA_Q(0, 0);
    BARF();
    // phase 1
    LDB_HALF(b, 1);
    STAGE_HALF(lA, Ag, ta, 1);
    MFMA_Q(0, 1);
    BARF();
    // phase 2 (B0 slot of this buffer dead after p1's barrier)
    LDA_HALF(b, 1);
    STAGE_HALF(lB, Bg, tb, 0);
    MFMA_Q(1, 0);
    BARF();
    // phase 3
    STAGE_HALF(lB, Bg, tb, 1);
    MFMA_Q(1, 1);
    asm volatile("s_waitcnt vmcnt(4)" ::: "memory");
    BARF();
  }
  asm volatile("s_waitcnt vmcnt(0)" ::: "memory");

#pragma unroll
  for (int mi = 0; mi < 8; ++mi)
#pragma unroll
    for (int n = 0; n < 4; ++n) {
      int col = bn * 256 + wn * 64 + n * 16 + fr;
      u16* Cd = C0;
      if (col >= NS) { Cd = C1; col -= NS; }
      const int row0 = bm * 256 + wm * 128 + mi * 16 + fq * 4;
#pragma unroll
      for (int j = 0; j < 4; ++j)
        Cd[(size_t)(row0 + j) * NS + col] = f2b(acc[mi][n][j]);
    }
}

// ===== split-K 8-phase 256^2 kernel: bf16 partials per z (same r12 phases) ==
__global__ __launch_bounds__(512, 2)
void k_gemm256s(const u16* __restrict__ A, const u16* __restrict__ Bt,
                u16* __restrict__ Cp, int M, int N, int K, int klen) {
  __shared__ u16 lA[2][256][64];
  __shared__ u16 lB[2][256][64];
  const int tid = threadIdx.x;
  const int w = tid >> 6, lane = tid & 63;
  const int wm = w >> 2, wn = w & 3;
  const int fr = lane & 15, fq = lane >> 4;
  const int xr = (fr & 7) << 4;
  const int sr = lane >> 3;
  const int sc = ((lane & 7) ^ sr) << 3;
  const int bn = blockIdx.x, bm = blockIdx.y, z = blockIdx.z;
  const int k0 = z * klen;
  const u16* Ag = A + (size_t)bm * 256 * K;
  const u16* Bg = Bt + (size_t)bn * 256 * K;
  const int NT = klen >> 6;
  u16* C = Cp + (size_t)z * M * N;

  f32x4 acc[8][4];
#pragma unroll
  for (int i = 0; i < 8; ++i)
#pragma unroll
    for (int j = 0; j < 4; ++j) acc[i][j] = (f32x4){0.f, 0.f, 0.f, 0.f};

  bf16x8 af[4][2];
  bf16x8 bfr[4][2];

#undef STAGE_HALF
#define STAGE_HALF(LT, G, TT, H) do {                                   \
    const int b_ = (TT) & 1; const int kt_ = ((TT) << 6) + k0;          \
    const u16* g0_ = (G) + (size_t)((H) * 128 + w * 8 + sr) * K + kt_ + sc; \
    u16* l0_ = &LT[b_][(H) * 128 + w * 8][0];                           \
    gl2lds16(g0_, l0_);                                                 \
    gl2lds16(g0_ + (size_t)64 * K, l0_ + 64 * 64);                      \
  } while (0)

  STAGE_HALF(lA, Ag, 0, 0); STAGE_HALF(lA, Ag, 0, 1);
  STAGE_HALF(lB, Bg, 0, 0); STAGE_HALF(lB, Bg, 0, 1);
  STAGE_HALF(lB, Bg, 1, 0); STAGE_HALF(lB, Bg, 1, 1);
  asm volatile("s_waitcnt vmcnt(4)" ::: "memory");
  BARF();

  for (int t = 0; t < NT; ++t) {
    const int b = t & 1;
    const int ta = (t + 1 == NT) ? 0 : t + 1;
    const int tb = (t + 2 >= NT) ? (t + 2 - NT) : t + 2;
    LDA_HALF(b, 0); LDB_HALF(b, 0);
    STAGE_HALF(lA, Ag, ta, 0);
    MFMA_Q(0, 0);
    BARF();
    LDB_HALF(b, 1);
    STAGE_HALF(lA, Ag, ta, 1);
    MFMA_Q(0, 1);
    BARF();
    LDA_HALF(b, 1);
    STAGE_HALF(lB, Bg, tb, 0);
    MFMA_Q(1, 0);
    BARF();
    STAGE_HALF(lB, Bg, tb, 1);
    MFMA_Q(1, 1);
    asm volatile("s_waitcnt vmcnt(4)" ::: "memory");
    BARF();
  }
  asm volatile("s_waitcnt vmcnt(0)" ::: "memory");

#undef STAGE_HALF
#undef LDA_HALF
#undef LDB_HALF
#undef MFMA_Q
#undef BARF

#pragma unroll
  for (int mi = 0; mi < 8; ++mi)
#pragma unroll
    for (int n = 0; n < 4; ++n) {
      const int col = bn * 256 + wn * 64 + n * 16 + fr;
      const int row0 = bm * 256 + wm * 128 + mi * 16 + fq * 4;
#pragma unroll
      for (int j = 0; j < 4; ++j)
        C[(size_t)(row0 + j) * N + col] = f2b(acc[mi][n][j]);
    }
}

// -------- reduce out_proj bf16 split-K partials -> fp32 output --------------
__global__ __launch_bounds__(256)
void k_ored(const u16* __restrict__ Cp, float* __restrict__ out) {
  const int i = blockIdx.x * 256 + threadIdx.x;   // over M*N/4
  f32x4 s = (f32x4){0.f, 0.f, 0.f, 0.f};
#pragma unroll
  for (int z = 0; z < KSPO; ++z) {
    ushort4 p = *(const ushort4*)&Cp[(size_t)z * L_DIM * H_DIM + (size_t)i * 4];
    s[0] += b2f(p.x); s[1] += b2f(p.y); s[2] += b2f(p.z); s[3] += b2f(p.w);
  }
  *(f32x4*)&out[(size_t)i * 4] = s;
}

// ---------------- bf16 MFMA GEMM (128x128, m97-style): C = A * Bt^T ---------
// fp32-output variant (dt_proj; fp32 dtraw proven best r10)
__global__ __launch_bounds__(256)
void k_gemm_bt(const u16* __restrict__ A, const u16* __restrict__ Bt,
               float* __restrict__ C, int M, int N, int K) {
  __shared__ u16 sA[128 * 64];
  __shared__ u16 sB[128 * 64];
  const int tid = threadIdx.x;
  const int wave = tid >> 6, lane = tid & 63;
  const int bn = blockIdx.x, bm = blockIdx.y;
  const int wm = wave >> 1, wn = wave & 1;
  const int fr = lane & 15, fq = lane >> 4;
  const int srow = lane >> 3;
  const int scol = (lane & 7) * 8;

  const u16* Ab = A + (size_t)bm * 128 * K;
  const u16* Bb = Bt + (size_t)bn * 128 * K;

  f32x4 acc[4][4];
#pragma unroll
  for (int i = 0; i < 4; ++i)
#pragma unroll
    for (int j = 0; j < 4; ++j) acc[i][j] = (f32x4){0.f, 0.f, 0.f, 0.f};

  for (int kt = 0; kt < K; kt += 64) {
    __syncthreads();
#pragma unroll
    for (int i = 0; i < 4; ++i) {
      int ci = wave * 4 + i;
      int row = ci * 8 + srow;
      gl2lds16(Ab + (size_t)row * K + kt + scol, &sA[ci * 512]);
      gl2lds16(Bb + (size_t)row * K + kt + scol, &sB[ci * 512]);
    }
    __syncthreads();
#pragma unroll
    for (int kk = 0; kk < 2; ++kk) {
      bf16x8 af[4], bfr[4];
#pragma unroll
      for (int mf = 0; mf < 4; ++mf)
        af[mf] = *(const bf16x8*)&sA[(wm * 64 + mf * 16 + fr) * 64 + kk * 32 + fq * 8];
#pragma unroll
      for (int nf = 0; nf < 4; ++nf)
        bfr[nf] = *(const bf16x8*)&sB[(wn * 64 + nf * 16 + fr) * 64 + kk * 32 + fq * 8];
#pragma unroll
      for (int mf = 0; mf < 4; ++mf)
#pragma unroll
        for (int nf = 0; nf < 4; ++nf)
          acc[mf][nf] = __builtin_amdgcn_mfma_f32_16x16x32_bf16(
              af[mf], bfr[nf], acc[mf][nf], 0, 0, 0);
    }
  }

#pragma unroll
  for (int mf = 0; mf < 4; ++mf)
#pragma unroll
    for (int nf = 0; nf < 4; ++nf) {
      int col = bn * 128 + wn * 64 + nf * 16 + fr;
#pragma unroll
      for (int j = 0; j < 4; ++j) {
        int row = bm * 128 + wm * 64 + mf * 16 + fq * 4 + j;
        C[(size_t)row * N + col] = acc[mf][nf][j];
      }
    }
}

// ---------------- split-K variant (blockIdx.z = K-slice), partial outputs ----
__global__ __launch_bounds__(256)
void k_gemm_bt_split(const u16* __restrict__ A, const u16* __restrict__ Bt,
                     float* __restrict__ Cp, int M, int N, int K, int klen) {
  __shared__ u16 sA[128 * 64];
  __shared__ u16 sB[128 * 64];
  const int tid = threadIdx.x;
  const int wave = tid >> 6, lane = tid & 63;
  const int bn = blockIdx.x, bm = blockIdx.y, z = blockIdx.z;
  const int wm = wave >> 1, wn = wave & 1;
  const int fr = lane & 15, fq = lane >> 4;
  const int srow = lane >> 3;
  const int scol = (lane & 7) * 8;
  const int k0 = z * klen;
  float* C = Cp + (size_t)z * M * N;

  const u16* Ab = A + (size_t)bm * 128 * K;
  const u16* Bb = Bt + (size_t)bn * 128 * K;

  f32x4 acc[4][4];
#pragma unroll
  for (int i = 0; i < 4; ++i)
#pragma unroll
    for (int j = 0; j < 4; ++j) acc[i][j] = (f32x4){0.f, 0.f, 0.f, 0.f};

  for (int kt = k0; kt < k0 + klen; kt += 64) {
    __syncthreads();
#pragma unroll
    for (int i = 0; i < 4; ++i) {
      int ci = wave * 4 + i;
      int row = ci * 8 + srow;
      gl2lds16(Ab + (size_t)row * K + kt + scol, &sA[ci * 512]);
      gl2lds16(Bb + (size_t)row * K + kt + scol, &sB[ci * 512]);
    }
    __syncthreads();
#pragma unroll
    for (int kk = 0; kk < 2; ++kk) {
      bf16x8 af[4], bfr[4];
#pragma unroll
      for (int mf = 0; mf < 4; ++mf)
        af[mf] = *(const bf16x8*)&sA[(wm * 64 + mf * 16 + fr) * 64 + kk * 32 + fq * 8];
#pragma unroll
      for (int nf = 0; nf < 4; ++nf)
        bfr[nf] = *(const bf16x8*)&sB[(wn * 64 + nf * 16 + fr) * 64 + kk * 32 + fq * 8];
#pragma unroll
      for (int mf = 0; mf < 4; ++mf)
#pragma unroll
        for (int nf = 0; nf < 4; ++nf)
          acc[mf][nf] = __builtin_amdgcn_mfma_f32_16x16x32_bf16(
              af[mf], bfr[nf], acc[mf][nf], 0, 0, 0);
    }
  }

#pragma unroll
  for (int mf = 0; mf < 4; ++mf)
#pragma unroll
    for (int nf = 0; nf < 4; ++nf) {
      int col = bn * 128 + wn * 64 + nf * 16 + fr;
#pragma unroll
      for (int j = 0; j < 4; ++j) {
        int row = bm * 128 + wm * 64 + mf * 16 + fq * 4 + j;
        C[(size_t)row * N + col] = acc[mf][nf][j];
      }
    }
}

// -------- reduce split-K partials -> ssm fp32; fuse time_step bf16 extract ---
__global__ __launch_bounds__(256)
void k_xred(const float* __restrict__ Cp, float* __restrict__ ssm,
            u16* __restrict__ tsb) {
  int i = blockIdx.x * 256 + threadIdx.x;   // over L*NPAD/4
  int l = i >> 6, g = i & 63;
  f32x4 s = (f32x4){0.f, 0.f, 0.f, 0.f};
#pragma unroll
  for (int z = 0; z < KSP; ++z)
    s += *(const f32x4*)&Cp[(size_t)z * L_DIM * NPAD + (size_t)l * NPAD + g * 4];
  *(f32x4*)&ssm[(size_t)l * NPAD + g * 4] = s;
  if (g < 32) {
    ushort4 o;
    o.x = f2b(s[0]); o.y = f2b(s[1]); o.z = f2b(s[2]); o.w = f2b(s[3]);
    *(ushort4*)&tsb[(size_t)l * R_TS + g * 4] = o;
  }
}

// ---------------- depthwise causal conv (K=4) + bias + silu -> bf16 ---------
// scalar r5-proven form
__global__ __launch_bounds__(256)
void k_conv_silu(const u16* __restrict__ Phid, const float* __restrict__ ck,
                 const float* __restrict__ cb, u16* __restrict__ hb) {
  int idx = blockIdx.x * 256 + threadIdx.x;       // l*D + d
  int l = idx >> 12, d = idx & (D_DIM - 1);
  float acc = cb[d];
#pragma unroll
  for (int k = 0; k < 4; ++k) {
    int ll = l - 3 + k;
    if (ll >= 0) acc = fmaf(b2f(Phid[(size_t)ll * D_DIM + d]), ck[d * 4 + k], acc);
  }
  float sv = acc / (1.f + __expf(-acc));
  hb[idx] = f2b(sv);
}

// ---------------- chunked selective scan (NC=64, CL=32) ----------------
__global__ __launch_bounds__(256)
void k_scan_partial(const float* __restrict__ dtraw, const float* __restrict__ b_dt,
                    const u16* __restrict__ hb, const float* __restrict__ ssm,
                    const float* __restrict__ A_log, float* __restrict__ sC,
                    float* __restrict__ aP) {
  __shared__ float sBl[CL][16];
  const int c = blockIdx.x >> 4;
  const int d = ((blockIdx.x & 15) << 8) + threadIdx.x;
  const int l0 = c * CL;
  {
    int t = threadIdx.x;
    if (t < CL * 4) {
      int r = t >> 2, j = (t & 3) * 4;
      *(float4*)&sBl[r][j] =
          *(const float4*)&ssm[(size_t)(l0 + r) * NPAD + R_TS + j];
    }
  }
  float Ac[N_ST];
#pragma unroll
  for (int n = 0; n < N_ST; ++n) Ac[n] = -__expf(A_log[d * N_ST + n]);
  const float bdt = b_dt[d];
  float s[N_ST], ap[N_ST];
#pragma unroll
  for (int n = 0; n < N_ST; ++n) { s[n] = 0.f; ap[n] = 1.f; }
  __syncthreads();

  float dtn = dtraw[(size_t)l0 * D_DIM + d];
  float hn = b2f(hb[(size_t)l0 * D_DIM + d]);
  for (int i = 0; i < CL; ++i) {
    const float x = dtn + bdt;
    const float hv = hn;
    const int ip = (i + 1 < CL) ? (i + 1) : i;
    dtn = dtraw[(size_t)(l0 + ip) * D_DIM + d];
    hn = b2f(hb[(size_t)(l0 + ip) * D_DIM + d]);
    const float dt = (x > 20.f) ? x : __logf(1.f + __expf(x));
    const float dth = dt * hv;
#pragma unroll
    for (int n = 0; n < N_ST; ++n) {
      float dA = __expf(Ac[n] * dt);
      s[n] = fmaf(dA, s[n], dth * sBl[i][n]);
      ap[n] *= dA;
    }
  }
  float* so = sC + ((size_t)c * D_DIM + d) * N_ST;
  float* ao = aP + ((size_t)c * D_DIM + d) * N_ST;
#pragma unroll
  for (int n = 0; n < N_ST; ++n) { so[n] = s[n]; ao[n] = ap[n]; }
}

__global__ __launch_bounds__(256)
void k_scan_combine(const float* __restrict__ sC, const float* __restrict__ aP,
                    float* __restrict__ init) {
  const int i = blockIdx.x * 256 + threadIdx.x;
  float s = 0.f;
  for (int c = 0; c < NC; ++c) {
    init[(size_t)c * (D_DIM * N_ST) + i] = s;
    s = fmaf(aP[(size_t)c * (D_DIM * N_ST) + i], s,
             sC[(size_t)c * (D_DIM * N_ST) + i]);
  }
}

__global__ __launch_bounds__(256)
void k_scan_final(const float* __restrict__ dtraw, const float* __restrict__ b_dt,
                  const u16* __restrict__ hb, const float* __restrict__ ssm,
                  const float* __restrict__ A_log, const float* __restrict__ init,
                  const u16* __restrict__ Pgate, const float* __restrict__ Dp,
                  u16* __restrict__ yb) {
  __shared__ float sBC[CL][32];
  const int c = blockIdx.x >> 4;
  const int d = ((blockIdx.x & 15) << 8) + threadIdx.x;
  const int l0 = c * CL;
  {
    int t = threadIdx.x;
    if (t < CL * 8) {
      int r = t >> 3, j = (t & 7) * 4;
      *(float4*)&sBC[r][j] =
          *(const float4*)&ssm[(size_t)(l0 + r) * NPAD + R_TS + j];
    }
  }
  float Ac[N_ST];
#pragma unroll
  for (int n = 0; n < N_ST; ++n) Ac[n] = -__expf(A_log[d * N_ST + n]);
  const float bdt = b_dt[d], dpd = Dp[d];
  float s[N_ST];
  const float* ini = init + ((size_t)c * D_DIM + d) * N_ST;
#pragma unroll
  for (int n = 0; n < N_ST; ++n) s[n] = ini[n];
  __syncthreads();

  float dtn = dtraw[(size_t)l0 * D_DIM + d];
  float hn = b2f(hb[(size_t)l0 * D_DIM + d]);
  float gn = b2f(Pgate[(size_t)l0 * D_DIM + d]);
  for (int i = 0; i < CL; ++i) {
    const float x = dtn + bdt;
    const float hv = hn;
    const float gv = gn;
    const int ip = (i + 1 < CL) ? (i + 1) : i;
    dtn = dtraw[(size_t)(l0 + ip) * D_DIM + d];
    hn = b2f(hb[(size_t)(l0 + ip) * D_DIM + d]);
    gn = b2f(Pgate[(size_t)(l0 + ip) * D_DIM + d]);
    const float dt = (x > 20.f) ? x : __logf(1.f + __expf(x));
    const float dth = dt * hv;
    float y = 0.f;
#pragma unroll
    for (int n = 0; n < N_ST; ++n) {
      float dA = __expf(Ac[n] * dt);
      s[n] = fmaf(dA, s[n], dth * sBC[i][n]);
      y = fmaf(s[n], sBC[i][16 + n], y);
    }
    y = fmaf(hv, dpd, y);
    const float sg = gv / (1.f + __expf(-gv));
    yb[(size_t)(l0 + i) * D_DIM + d] = f2b(y * sg);
  }
}

// ---------------- launcher ----------------
extern "C" void kernel_launch(void* const* d_in, const int* in_sizes, int n_in,
                              void* d_out, int out_size, void* d_ws, size_t ws_size,
                              hipStream_t stream) {
  const float* X     = (const float*)d_in[0];
  const float* W_in  = (const float*)d_in[1];
  const float* ck    = (const float*)d_in[2];
  const float* cb    = (const float*)d_in[3];
  const float* W_x   = (const float*)d_in[4];
  const float* W_dt  = (const float*)d_in[5];
  const float* b_dt  = (const float*)d_in[6];
  const float* W_out = (const float*)d_in[7];
  const float* A_log = (const float*)d_in[8];
  const float* Dp    = (const float*)d_in[9];

  char* w = (char*)d_ws;
  size_t off = 0;
  auto alloc = [&](size_t bytes) {
    void* p = w + off;
    off = (off + bytes + 255) & ~(size_t)255;
    return p;
  };
  u16*   Xb    = (u16*)  alloc((size_t)L_DIM * H_DIM * 2);        //  0.0 -  8.4 MB
  u16*   WinT  = (u16*)  alloc((size_t)2 * D_DIM * H_DIM * 2);    //  8.4 - 42.0
  u16*   Phid  = (u16*)  alloc((size_t)L_DIM * D_DIM * 2);        // 42.0 - 58.8
  u16*   Pgate = (u16*)  alloc((size_t)L_DIM * D_DIM * 2);        // 58.8 - 75.6
  u16*   hb    = (u16*)  alloc((size_t)L_DIM * D_DIM * 2);        // 75.6 - 92.4
  u16*   WxT   = (u16*)  alloc((size_t)NPAD * D_DIM * 2);
  float* ssm   = (float*)alloc((size_t)L_DIM * NPAD * 4);
  u16*   tsb   = (u16*)  alloc((size_t)L_DIM * R_TS * 2);
  u16*   WdtT  = (u16*)  alloc((size_t)D_DIM * R_TS * 2);
  float* dtraw = (float*)alloc((size_t)L_DIM * D_DIM * 4);        // fp32 (r10 cfg)
  u16*   WoutT = (u16*)  alloc((size_t)H_DIM * D_DIM * 2);
  u16*   yb    = (u16*)  alloc((size_t)L_DIM * D_DIM * 2);        // ~166 MB linear
  // Aliases (disjoint lifetimes, round-5-proven layout):
  //  xpart (16.8 MB, steps 6-7)       @0      (Xb+WinT dead after step 3)
  //  sCb/aPb (2x16.8 MB, steps 10-11) @0/16.8 (same dead region)
  //  initb (16.8 MB, steps 11-12)     @Phid   (dead after step 4; exact fit)
  //  opartb bf16 (33.6 MB, steps 14-15) @0    (Xb+WinT region, dead by 14)
  float* xpart  = (float*)d_ws;
  float* sCb    = (float*)d_ws;
  float* aPb    = (float*)((char*)d_ws + (size_t)NC * D_DIM * N_ST * 4);
  float* initb  = (float*)Phid;
  u16*   opartb = (u16*)d_ws;
  (void)ws_size;

  // 1) fused preprocessing: X->bf16 + W_in/W_x/W_dt/W_out transposes
  k_prep<<<PREP_NB, 256, 0, stream>>>(
      X, Xb, W_in, WinT, W_x, WxT, W_dt, WdtT, W_out, WoutT);
  // 3) {Phid|Pgate} = X * W_in   (8-phase 256^2, bf16 outputs)
  k_gemm256<<<dim3(2 * D_DIM / 256, L_DIM / 256), 512, 0, stream>>>(
      Xb, WinT, Phid, Pgate, L_DIM, 2 * D_DIM, H_DIM, D_DIM);
  // 4) conv + silu -> hb (bf16), scalar form
  k_conv_silu<<<L_DIM * D_DIM / 256, 256, 0, stream>>>(Phid, ck, cb, hb);
  // 6-7) ssm partials = h * W_x  (split-K=8), reduce + ts extract
  k_gemm_bt_split<<<dim3(NPAD / 128, L_DIM / 128, KSP), 256, 0, stream>>>(
      hb, WxT, xpart, L_DIM, NPAD, D_DIM, D_DIM / KSP);
  k_xred<<<L_DIM * NPAD / 4 / 256, 256, 0, stream>>>(xpart, ssm, tsb);
  // 9) dtraw = ts * W_dt  [L, D]  (fp32 out)
  k_gemm_bt<<<dim3(D_DIM / 128, L_DIM / 128), 256, 0, stream>>>(
      tsb, WdtT, dtraw, L_DIM, D_DIM, R_TS);
  // 10-12) chunked scan (NC=64 chunks of CL=32)
  k_scan_partial<<<NC * (D_DIM / 256), 256, 0, stream>>>(
      dtraw, b_dt, hb, ssm, A_log, sCb, aPb);
  k_scan_combine<<<D_DIM * N_ST / 256, 256, 0, stream>>>(sCb, aPb, initb);
  k_scan_final<<<NC * (D_DIM / 256), 256, 0, stream>>>(
      dtraw, b_dt, hb, ssm, A_log, initb, Pgate, Dp, yb);
  // 14-15) out = y * W_out  (8-phase 256^2, split-K=4, bf16 partials) + reduce
  k_gemm256s<<<dim3(H_DIM / 256, L_DIM / 256, KSPO), 512, 0, stream>>>(
      yb, WoutT, opartb, L_DIM, H_DIM, D_DIM, D_DIM / KSPO);
  k_ored<<<L_DIM * H_DIM / 4 / 256, 256, 0, stream>>>(opartb, (float*)d_out);
}